// Round 8
// baseline (819.216 us; speedup 1.0000x reference)
//
#include <hip/hip_runtime.h>
#include <hip/hip_bf16.h>
#include <cstdint>
#include <cstddef>

#define TT 128
#define BBATCH 256
#define FFEAT 76
#define HDIM 64
#define NHEAD 4
#define DKH 16
#define DFF1 256
#define AH1 8
#define NROWS (BBATCH * FFEAT)   // 19456
#define FC 19                    // features per pipeline chunk (4 chunks)

#define LOG2E 1.4426950408889634f

typedef __attribute__((ext_vector_type(8))) short bf16x8;
typedef __attribute__((ext_vector_type(4))) float f32x4;

__device__ __forceinline__ float fast_sigmoid(float v) {
    float p = __builtin_amdgcn_exp2f(-v * LOG2E);
    return __builtin_amdgcn_rcpf(1.0f + p);
}
__device__ __forceinline__ float fast_tanh(float v) {
    float p = __builtin_amdgcn_exp2f(v * (2.0f * LOG2E));
    return 1.0f - 2.0f * __builtin_amdgcn_rcpf(1.0f + p);
}
__device__ __forceinline__ short f2bf(float x) {
    __hip_bfloat16 h = __float2bfloat16(x);
    return *reinterpret_cast<short*>(&h);
}
__device__ __forceinline__ float bf2f(unsigned short s) {
    return __uint_as_float(((unsigned)s) << 16);
}
__device__ __forceinline__ unsigned pack_bf16(float a, float b) {
    unsigned ua = (unsigned)(unsigned short)f2bf(a);
    unsigned ub = (unsigned)(unsigned short)f2bf(b);
    return ua | (ub << 16);
}

// ---------------------------------------------------------------------------
// FUSED scan+attention kernel (R8): role-split grid overlaps the latency/
// pipe-bound GRU scan (chunk k) with the memory-bound time-attention
// (chunk k-1) in the same dispatch. Scan leaves HBM ~84% and VALU ~59% idle
// (R3-R7 counters); attn waves fill that. Blocks gid < ngru run the VERBATIM
// R3 scan (155us/38-feat proven); the rest run the verbatim v3 online-
// softmax attention as 1-wave blocks. hs is double-buffered across launches;
// no intra-launch data dependency.
// ---------------------------------------------------------------------------
__global__ __launch_bounds__(64) void fused_scan_attn_kernel(
    const float* __restrict__ x, const float* __restrict__ w_ih,
    const float* __restrict__ w_hh, const float* __restrict__ b_ih,
    const float* __restrict__ b_hh, const float* __restrict__ Wt,
    const float* __restrict__ Wx, const float* __restrict__ rate,
    int ngru, int f0_gru, __hip_bfloat16* __restrict__ hs_w,
    int f0_att, const __hip_bfloat16* __restrict__ hs_r,
    float* __restrict__ wtil, float* __restrict__ emb)
{
    __shared__ float x_lds[TT][16];
    __shared__ float wt_s[64][8];
    __shared__ float wx_s[64][8];
    __shared__ short hx[16][72];
    __shared__ float q_s[16][8];

    const int gid  = blockIdx.x;
    const int lane = threadIdx.x;

    if (gid < ngru) {
        // ---------------- GRU scan role (verbatim R3) ----------------
        const int f_loc = gid >> 4;
        const int f     = f0_gru + f_loc;
        const int b0    = (gid & 15) * 16;
        const int c     = lane & 15;
        const int q     = lane >> 4;

        for (int i = lane; i < TT * 16; i += 64) {
            int t = i >> 4, b = i & 15;
            x_lds[t][b] = x[((size_t)t * BBATCH + b0 + b) * FFEAT + f];
        }
        for (int i = lane; i < 512; i += 64) {
            ((float*)wt_s)[i] = Wt[(size_t)f * 512 + i];
            ((float*)wx_s)[i] = Wx[(size_t)f * 512 + i];
        }
        __syncthreads();

        bf16x8 afr[12][2];
        {
            const float* whh_f = w_hh + (size_t)f * 192 * 64;
            #pragma unroll
            for (int nt = 0; nt < 12; ++nt) {
                int gate = nt >> 2, tt = nt & 3;
                int urow = (c >> 2) * 8 + (tt & 1) * 4 + (c & 3) + (tt >> 1) * 32;
                const float* row = whh_f + (size_t)(gate * 64 + urow) * 64;
                #pragma unroll
                for (int kq = 0; kq < 2; ++kq) {
                    bf16x8 fr;
                    #pragma unroll
                    for (int j = 0; j < 8; ++j) fr[j] = f2bf(row[kq * 32 + q * 8 + j]);
                    afr[nt][kq] = fr;
                }
            }
        }
        float wr[4][4], wz[4][4], wn[4][4], bnx[4][4];
        f32x4 biasv[12];
        #pragma unroll
        for (int tt = 0; tt < 4; ++tt) {
            #pragma unroll
            for (int r = 0; r < 4; ++r) {
                int u = q * 8 + (tt & 1) * 4 + r + (tt >> 1) * 32;
                wr[tt][r]  = w_ih[f*192 + u];
                wz[tt][r]  = w_ih[f*192 + 64 + u];
                wn[tt][r]  = w_ih[f*192 + 128 + u];
                bnx[tt][r] = b_ih[f*192 + 128 + u];
                biasv[tt][r]     = b_ih[f*192 + u]      + b_hh[f*192 + u];
                biasv[4 + tt][r] = b_ih[f*192 + 64 + u] + b_hh[f*192 + 64 + u];
                biasv[8 + tt][r] = b_hh[f*192 + 128 + u];
            }
        }

        float hprev[4][4];
        #pragma unroll
        for (int tt = 0; tt < 4; ++tt)
            #pragma unroll
            for (int r = 0; r < 4; ++r) hprev[tt][r] = 0.f;

        bf16x8 hb0 = {0,0,0,0,0,0,0,0};
        bf16x8 hb1 = {0,0,0,0,0,0,0,0};

        short* hs_b = (short*)hs_w + ((size_t)f_loc * BBATCH + b0 + c) * TT * HDIM;

        for (int t = 0; t < TT; ++t) {
            f32x4 acc[12];
            #pragma unroll
            for (int nt = 0; nt < 12; ++nt) {
                f32x4 a = __builtin_amdgcn_mfma_f32_16x16x32_bf16(afr[nt][0], hb0, biasv[nt], 0, 0, 0);
                acc[nt]  = __builtin_amdgcn_mfma_f32_16x16x32_bf16(afr[nt][1], hb1, a, 0, 0, 0);
            }

            float xv = x_lds[t][c];
            float hn4[4][4];
            #pragma unroll
            for (int tt = 0; tt < 4; ++tt) {
                #pragma unroll
                for (int r = 0; r < 4; ++r) {
                    float R  = fmaf(xv, wr[tt][r], acc[tt][r]);
                    float Z  = fmaf(xv, wz[tt][r], acc[4 + tt][r]);
                    float NX = fmaf(xv, wn[tt][r], bnx[tt][r]);
                    float rg = fast_sigmoid(R);
                    float zg = fast_sigmoid(Z);
                    float ng = fast_tanh(fmaf(rg, acc[8 + tt][r], NX));
                    float hn = fmaf(zg, hprev[tt][r] - ng, ng);
                    hprev[tt][r] = hn;
                    hn4[tt][r] = hn;
                }
            }
            {
                union { int4 i; bf16x8 v; } u0, u1;
                u0.i.x = pack_bf16(hn4[0][0], hn4[0][1]);
                u0.i.y = pack_bf16(hn4[0][2], hn4[0][3]);
                u0.i.z = pack_bf16(hn4[1][0], hn4[1][1]);
                u0.i.w = pack_bf16(hn4[1][2], hn4[1][3]);
                u1.i.x = pack_bf16(hn4[2][0], hn4[2][1]);
                u1.i.y = pack_bf16(hn4[2][2], hn4[2][3]);
                u1.i.z = pack_bf16(hn4[3][0], hn4[3][1]);
                u1.i.w = pack_bf16(hn4[3][2], hn4[3][3]);
                hb0 = u0.v; hb1 = u1.v;
            }
            short* dst = hs_b + (size_t)t * HDIM + q * 8;
            *(bf16x8*)dst = hb0;
            *(bf16x8*)(dst + 32) = hb1;
        }

        *(bf16x8*)&hx[c][q * 8]      = hb0;
        *(bf16x8*)&hx[c][32 + q * 8] = hb1;

        #pragma unroll
        for (int rr = 0; rr < 2; ++rr) {
            int role = rr * 64 + lane;
            int b = role >> 3, a = role & 7;
            float s = 0.f;
            #pragma unroll 8
            for (int j = 0; j < 64; ++j)
                s = fmaf(bf2f((unsigned short)hx[b][j]), wt_s[j][a], s);
            q_s[b][a] = s;
        }
        {
            int b = lane >> 2, jb = (lane & 3) * 16;
            float qreg[8];
            #pragma unroll
            for (int a = 0; a < 8; ++a) qreg[a] = q_s[b][a];
            float* wt_out = wtil + ((size_t)(b0 + b) * FFEAT + f) * HDIM + jb;
            #pragma unroll
            for (int j4 = 0; j4 < 4; ++j4) {
                float4 v;
                #pragma unroll
                for (int jj = 0; jj < 4; ++jj) {
                    int j = jb + j4 * 4 + jj;
                    float s = 0.f;
                    #pragma unroll
                    for (int a = 0; a < 8; ++a) s = fmaf(wx_s[j][a], qreg[a], s);
                    (&v.x)[jj] = s;
                }
                *(float4*)&wt_out[j4 * 4] = v;
            }
        }
    } else {
        // ------------- time-attention role (verbatim v3, 1 wave) -------------
        const int aid   = gid - ngru;
        const int b     = aid & 255;
        const int f_loc = aid >> 8;
        const int f     = f0_att + f_loc;
        const int g     = lane >> 3;
        const int i     = lane & 7;

        float wv[8];
        {
            const float4* src = (const float4*)(wtil + ((size_t)b * FFEAT + f) * HDIM + 8 * i);
            float4 a = src[0], c2 = src[1];
            wv[0]=a.x; wv[1]=a.y; wv[2]=a.z; wv[3]=a.w;
            wv[4]=c2.x; wv[5]=c2.y; wv[6]=c2.z; wv[7]=c2.w;
        }
        const float rs = fast_sigmoid(rate[f]);
        const uint4* basev = (const uint4*)((const short*)hs_r +
                              ((size_t)f_loc * BBATCH + b) * TT * HDIM);

        float m = -1.0e30f, s = 0.f;
        float o[8];
        #pragma unroll
        for (int j = 0; j < 8; ++j) o[j] = 0.f;

        #pragma unroll 4
        for (int it = 0; it < 16; ++it) {
            const int t = it * 8 + g;
            uint4 U = basev[t * 8 + i];
            float h[8];
            h[0] = __uint_as_float(U.x << 16); h[1] = __uint_as_float(U.x & 0xffff0000u);
            h[2] = __uint_as_float(U.y << 16); h[3] = __uint_as_float(U.y & 0xffff0000u);
            h[4] = __uint_as_float(U.z << 16); h[5] = __uint_as_float(U.z & 0xffff0000u);
            h[6] = __uint_as_float(U.w << 16); h[7] = __uint_as_float(U.w & 0xffff0000u);
            float dp = 0.f;
            #pragma unroll
            for (int j = 0; j < 8; ++j) dp = fmaf(h[j], wv[j], dp);
            dp += __shfl_xor(dp, 1, 64);
            dp += __shfl_xor(dp, 2, 64);
            dp += __shfl_xor(dp, 4, 64);
            float sig = fast_sigmoid(dp);
            float den = rs * (__logf(2.72f + (1.0f - sig)) * (float)(TT - t));
            float e = fmaxf(sig / den, 0.0f);
            float nm = fmaxf(m, e);
            float sc = __builtin_amdgcn_exp2f((m - nm) * LOG2E);
            float p  = __builtin_amdgcn_exp2f((e - nm) * LOG2E);
            s = fmaf(s, sc, p);
            #pragma unroll
            for (int j = 0; j < 8; ++j) o[j] = fmaf(o[j], sc, p * h[j]);
            m = nm;
        }
        #pragma unroll
        for (int k = 8; k <= 32; k <<= 1) {
            float om = __shfl_xor(m, k, 64);
            float os = __shfl_xor(s, k, 64);
            float nm = fmaxf(m, om);
            float sa = __builtin_amdgcn_exp2f((m - nm) * LOG2E);
            float sb = __builtin_amdgcn_exp2f((om - nm) * LOG2E);
            s = s * sa + os * sb;
            #pragma unroll
            for (int j = 0; j < 8; ++j) {
                float oo = __shfl_xor(o[j], k, 64);
                o[j] = o[j] * sa + oo * sb;
            }
            m = nm;
        }
        if (g == 0) {
            float inv = __builtin_amdgcn_rcpf(s);
            float4 v0, v1;
            v0.x = o[0]*inv; v0.y = o[1]*inv; v0.z = o[2]*inv; v0.w = o[3]*inv;
            v1.x = o[4]*inv; v1.y = o[5]*inv; v1.z = o[6]*inv; v1.w = o[7]*inv;
            float* dst = &emb[((size_t)b * FFEAT + f) * HDIM + 8 * i];
            *(float4*)dst       = v0;
            *(float4*)(dst + 4) = v1;
        }
    }
}

// ---------------------------------------------------------------------------
// Tail: tiled GEMM + MHA core + final head (proven split kernels, unchanged).
// ---------------------------------------------------------------------------
struct GemmP {
    const float* X;
    const float* W[3];
    const float* B[3];
    const float* R;
    float* Y[3];
    int K;
    int Nfull;
    int act;
};

__global__ __launch_bounds__(256) void gemm_kernel(GemmP A)
{
    __shared__ float xs[64][65];
    __shared__ float ws[64][68];

    const int tid = threadIdx.x;
    const int tx  = tid & 15;
    const int ty  = tid >> 4;
    const int m0  = blockIdx.x * 64;
    const int n0  = blockIdx.y * 64;
    const int z   = blockIdx.z;

    const float* W = A.W[z];
    const float* Bv = A.B[z];
    float* Y = A.Y[z];
    const int K = A.K, Nfull = A.Nfull;

    float acc[4][4];
    #pragma unroll
    for (int i = 0; i < 4; ++i)
        #pragma unroll
        for (int j = 0; j < 4; ++j) acc[i][j] = 0.f;

    for (int kc = 0; kc < K; kc += 64) {
        for (int s = tid; s < 1024; s += 256) {
            int row = s >> 4, c4 = s & 15;
            float4 xv = *(const float4*)&A.X[(size_t)(m0 + row) * K + kc + 4*c4];
            xs[row][4*c4+0] = xv.x; xs[row][4*c4+1] = xv.y;
            xs[row][4*c4+2] = xv.z; xs[row][4*c4+3] = xv.w;
            float4 wv = *(const float4*)&W[(size_t)(kc + row) * Nfull + n0 + 4*c4];
            *(float4*)&ws[row][4*c4] = wv;
        }
        __syncthreads();
        #pragma unroll 16
        for (int k = 0; k < 64; ++k) {
            float a0 = xs[4*ty+0][k], a1 = xs[4*ty+1][k];
            float a2 = xs[4*ty+2][k], a3 = xs[4*ty+3][k];
            float4 wv = *(const float4*)&ws[k][4*tx];
            #pragma unroll
            for (int j = 0; j < 4; ++j) {
                float wj = (&wv.x)[j];
                acc[0][j] = fmaf(a0, wj, acc[0][j]);
                acc[1][j] = fmaf(a1, wj, acc[1][j]);
                acc[2][j] = fmaf(a2, wj, acc[2][j]);
                acc[3][j] = fmaf(a3, wj, acc[3][j]);
            }
        }
        __syncthreads();
    }

    float4 bias = *(const float4*)&Bv[n0 + 4*tx];
    #pragma unroll
    for (int i = 0; i < 4; ++i) {
        int row = m0 + 4*ty + i;
        float4 v;
        v.x = acc[i][0] + bias.x; v.y = acc[i][1] + bias.y;
        v.z = acc[i][2] + bias.z; v.w = acc[i][3] + bias.w;
        if (A.act) {
            v.x = fmaxf(v.x, 0.f); v.y = fmaxf(v.y, 0.f);
            v.z = fmaxf(v.z, 0.f); v.w = fmaxf(v.w, 0.f);
        }
        if (A.R) {
            float4 r4 = *(const float4*)&A.R[(size_t)row * Nfull + n0 + 4*tx];
            v.x += r4.x; v.y += r4.y; v.z += r4.z; v.w += r4.w;
        }
        *(float4*)&Y[(size_t)row * Nfull + n0 + 4*tx] = v;
    }
}

__global__ __launch_bounds__(256) void mha_core_kernel(
    const float* __restrict__ q, const float* __restrict__ k,
    const float* __restrict__ v, float* __restrict__ ctx)
{
    const int b  = blockIdx.x;
    const int hh = blockIdx.y;
    const int tid = threadIdx.x;

    __shared__ float qs[FFEAT][17];
    __shared__ float ks[FFEAT][17];
    __shared__ float vs[FFEAT][17];
    __shared__ float ps[FFEAT][77];

    for (int idx = tid; idx < FFEAT * DKH; idx += 256) {
        int i = idx >> 4, c = idx & 15;
        size_t g = ((size_t)b * FFEAT + i) * HDIM + hh * DKH + c;
        qs[i][c] = q[g]; ks[i][c] = k[g]; vs[i][c] = v[g];
    }
    __syncthreads();

    for (int idx = tid; idx < FFEAT * FFEAT; idx += 256) {
        int i = idx / FFEAT, j = idx % FFEAT;
        float acc = 0.f;
        #pragma unroll
        for (int c = 0; c < DKH; ++c) acc = fmaf(qs[i][c], ks[j][c], acc);
        ps[i][j] = acc * 0.25f;
    }
    __syncthreads();

    if (tid < FFEAT) {
        float mm = ps[tid][0];
        #pragma unroll 4
        for (int j = 1; j < FFEAT; ++j) mm = fmaxf(mm, ps[tid][j]);
        float ss = 0.f;
        #pragma unroll 4
        for (int j = 0; j < FFEAT; ++j) {
            float pv = __builtin_amdgcn_exp2f((ps[tid][j] - mm) * LOG2E);
            ps[tid][j] = pv; ss += pv;
        }
        float inv = 1.0f / ss;
        #pragma unroll 4
        for (int j = 0; j < FFEAT; ++j) ps[tid][j] *= inv;
    }
    __syncthreads();

    for (int idx = tid; idx < FFEAT * DKH; idx += 256) {
        int i = idx >> 4, c = idx & 15;
        float acc = 0.f;
        #pragma unroll 4
        for (int j = 0; j < FFEAT; ++j) acc = fmaf(ps[i][j], vs[j][c], acc);
        ctx[((size_t)b * FFEAT + i) * HDIM + hh * DKH + c] = acc;
    }
}

__global__ __launch_bounds__(128) void final_kernel(
    const float* __restrict__ ctx3, const float* __restrict__ fk,
    const float* __restrict__ fv,
    const float* __restrict__ faq, const float* __restrict__ fabq,
    const float* __restrict__ o0w, const float* __restrict__ o0b,
    const float* __restrict__ o1w, const float* __restrict__ o1b,
    float* __restrict__ out)
{
    const int b = blockIdx.x;
    const int tid = threadIdx.x;

    __shared__ float last[HDIM];
    __shared__ float fqs[HDIM];
    __shared__ float sm[FFEAT];
    __shared__ float vv[HDIM];
    __shared__ float hh[HDIM];
    __shared__ float redm[2], redp[2];

    if (tid < HDIM) last[tid] = ctx3[((size_t)b * FFEAT + FFEAT - 1) * HDIM + tid];
    __syncthreads();
    if (tid < HDIM) {
        float acc = fabq[tid];
        #pragma unroll 8
        for (int j = 0; j < HDIM; ++j) acc = fmaf(last[j], faq[j * HDIM + tid], acc);
        fqs[tid] = acc;
    }
    __syncthreads();

    float e = -3.0e38f;
    if (tid < FFEAT) {
        const float4* kr = (const float4*)&fk[((size_t)b * FFEAT + tid) * HDIM];
        float acc = 0.f;
        #pragma unroll
        for (int c4 = 0; c4 < 16; ++c4) {
            float4 kv = kr[c4];
            acc = fmaf(kv.x, fqs[4*c4+0], acc);
            acc = fmaf(kv.y, fqs[4*c4+1], acc);
            acc = fmaf(kv.z, fqs[4*c4+2], acc);
            acc = fmaf(kv.w, fqs[4*c4+3], acc);
        }
        e = acc;
    }
    float m = e;
    #pragma unroll
    for (int off = 32; off > 0; off >>= 1) m = fmaxf(m, __shfl_xor(m, off, 64));
    if ((tid & 63) == 0) redm[tid >> 6] = m;
    __syncthreads();
    m = fmaxf(redm[0], redm[1]);
    float p = (tid < FFEAT) ? __builtin_amdgcn_exp2f((e - m) * LOG2E) : 0.f;
    float s = p;
    #pragma unroll
    for (int off = 32; off > 0; off >>= 1) s += __shfl_xor(s, off, 64);
    if ((tid & 63) == 0) redp[tid >> 6] = s;
    __syncthreads();
    s = redp[0] + redp[1];
    if (tid < FFEAT) sm[tid] = p / s;
    __syncthreads();

    if (tid < HDIM) {
        float acc = 0.f;
        for (int ff = 0; ff < FFEAT; ++ff)
            acc = fmaf(sm[ff], fv[((size_t)b * FFEAT + ff) * HDIM + tid], acc);
        vv[tid] = acc;
    }
    __syncthreads();
    if (tid < HDIM) {
        float acc = o0b[tid];
        #pragma unroll 8
        for (int j = 0; j < HDIM; ++j) acc = fmaf(vv[j], o0w[j * HDIM + tid], acc);
        hh[tid] = fmaxf(acc, 0.f);
    }
    __syncthreads();
    if (tid < 64) {
        float t = hh[tid] * o1w[tid];
        #pragma unroll
        for (int off = 32; off > 0; off >>= 1) t += __shfl_xor(t, off, 64);
        if (tid == 0) out[b] = fast_sigmoid(t + o1b[0]);
    }
}

__global__ void ws_report_kernel(float* out, int n, float ws_mib) {
    int i = blockIdx.x * blockDim.x + threadIdx.x;
    if (i < n) out[i] = ws_mib;
}

extern "C" void kernel_launch(void* const* d_in, const int* in_sizes, int n_in,
                              void* d_out, int out_size, void* d_ws, size_t ws_size,
                              hipStream_t stream)
{
    const float* x     = (const float*)d_in[0];
    const float* w_ih  = (const float*)d_in[1];
    const float* w_hh  = (const float*)d_in[2];
    const float* b_ih  = (const float*)d_in[3];
    const float* b_hh  = (const float*)d_in[4];
    const float* attWt = (const float*)d_in[5];
    const float* attWx = (const float*)d_in[6];
    const float* attRt = (const float*)d_in[7];
    const float* wq    = (const float*)d_in[8];
    const float* bq    = (const float*)d_in[9];
    const float* wk    = (const float*)d_in[10];
    const float* bk    = (const float*)d_in[11];
    const float* wv    = (const float*)d_in[12];
    const float* bv    = (const float*)d_in[13];
    const float* wo    = (const float*)d_in[14];
    const float* bo    = (const float*)d_in[15];
    const float* w1    = (const float*)d_in[16];
    const float* b1    = (const float*)d_in[17];
    const float* w2    = (const float*)d_in[18];
    const float* b2    = (const float*)d_in[19];
    const float* faq   = (const float*)d_in[20];
    const float* fabq  = (const float*)d_in[21];
    const float* fak   = (const float*)d_in[22];
    const float* fabk  = (const float*)d_in[23];
    const float* fav   = (const float*)d_in[24];
    const float* fabv  = (const float*)d_in[25];
    const float* o0w   = (const float*)d_in[26];
    const float* o0b   = (const float*)d_in[27];
    const float* o1w   = (const float*)d_in[28];
    const float* o1b   = (const float*)d_in[29];
    float* out = (float*)d_out;

    const size_t emb_bytes  = (size_t)NROWS * HDIM * 4;                 // 4.98 MB
    const size_t wtil_bytes = (size_t)NROWS * HDIM * 4;                 // 4.98 MB
    const size_t hs_half    = (size_t)FC * BBATCH * TT * HDIM * 2;      // 39.85 MB
    const size_t R64        = (size_t)NROWS * HDIM;
    const size_t tail_bytes = 12 * R64 * 4;                             // 59.8 MB
    const size_t scratch_sz = (2 * hs_half > tail_bytes) ? 2 * hs_half : tail_bytes;
    const size_t need = emb_bytes + wtil_bytes + scratch_sz;            // ~89.7 MB

    if (need > ws_size) {
        ws_report_kernel<<<dim3((out_size + 255) / 256), dim3(256), 0, stream>>>(
            out, out_size, (float)((double)ws_size / (1024.0 * 1024.0)));
        return;
    }

    float* emb  = (float*)d_ws;
    float* wtil = (float*)((char*)d_ws + emb_bytes);
    char*  scratch = (char*)d_ws + emb_bytes + wtil_bytes;
    __hip_bfloat16* hs[2] = {
        (__hip_bfloat16*)scratch,
        (__hip_bfloat16*)(scratch + hs_half)
    };

    // Software pipeline: launch k runs gru(chunk k) + attn(chunk k-1).
    const int NCHUNK = FFEAT / FC;   // 4
    for (int c = 0; c <= NCHUNK; ++c) {
        const int gru_on = (c < NCHUNK);
        const int att_on = (c > 0);
        const int ngru = gru_on ? 16 * FC : 0;
        const int natt = att_on ? BBATCH * FC : 0;
        fused_scan_attn_kernel<<<dim3(ngru + natt), dim3(64), 0, stream>>>(
            x, w_ih, w_hh, b_ih, b_hh, attWt, attWx, attRt,
            ngru, c * FC, hs[c & 1],
            (c - 1) * FC, hs[(c - 1) & 1],
            wtil, emb);
    }

    float* ts   = (float*)scratch;
    float* q    = ts;
    float* k    = ts + 1*R64;
    float* v    = ts + 2*R64;
    float* ctx  = ts + 3*R64;
    float* ctx2 = ts + 4*R64;
    float* hid  = ts + 5*R64;
    float* ctx3 = ts + 9*R64;
    float* fk   = ts + 10*R64;
    float* fv   = ts + 11*R64;

    const int MB = NROWS / 64;

    {
        GemmP A = { emb, {wq, wk, wv}, {bq, bk, bv}, nullptr, {q, k, v}, 64, 64, 0 };
        gemm_kernel<<<dim3(MB, 1, 3), dim3(256), 0, stream>>>(A);
    }
    mha_core_kernel<<<dim3(BBATCH, NHEAD), dim3(256), 0, stream>>>(q, k, v, ctx);
    {
        GemmP A = { ctx, {wo, nullptr, nullptr}, {bo, nullptr, nullptr}, emb,
                    {ctx2, nullptr, nullptr}, 64, 64, 0 };
        gemm_kernel<<<dim3(MB, 1, 1), dim3(256), 0, stream>>>(A);
    }
    {
        GemmP A = { ctx2, {w1, nullptr, nullptr}, {b1, nullptr, nullptr}, nullptr,
                    {hid, nullptr, nullptr}, 64, 256, 1 };
        gemm_kernel<<<dim3(MB, 4, 1), dim3(256), 0, stream>>>(A);
    }
    {
        GemmP A = { hid, {w2, nullptr, nullptr}, {b2, nullptr, nullptr}, ctx2,
                    {ctx3, nullptr, nullptr}, 256, 64, 0 };
        gemm_kernel<<<dim3(MB, 1, 1), dim3(256), 0, stream>>>(A);
    }
    {
        GemmP A = { ctx3, {fak, fav, nullptr}, {fabk, fabv, nullptr}, nullptr,
                    {fk, fv, nullptr}, 64, 64, 0 };
        gemm_kernel<<<dim3(MB, 1, 2), dim3(256), 0, stream>>>(A);
    }
    final_kernel<<<dim3(BBATCH), dim3(128), 0, stream>>>(
        ctx3, fk, fv, faq, fabq, o0w, o0b, o1w, o1b, out);
}

// Round 9
// 638.976 us; speedup vs baseline: 1.2821x; 1.2821x over previous
//
#include <hip/hip_runtime.h>
#include <hip/hip_bf16.h>
#include <cstdint>
#include <cstddef>

#define TT 128
#define BBATCH 256
#define FFEAT 76
#define HDIM 64
#define NHEAD 4
#define DKH 16
#define DFF1 256
#define AH1 8
#define NROWS (BBATCH * FFEAT)   // 19456

#define LOG2E 1.4426950408889634f

typedef __attribute__((ext_vector_type(8))) short bf16x8;
typedef __attribute__((ext_vector_type(4))) float f32x4;

__device__ __forceinline__ float fast_sigmoid(float v) {
    float p = __builtin_amdgcn_exp2f(-v * LOG2E);
    return __builtin_amdgcn_rcpf(1.0f + p);
}
__device__ __forceinline__ float fast_tanh(float v) {
    float p = __builtin_amdgcn_exp2f(v * (2.0f * LOG2E));
    return 1.0f - 2.0f * __builtin_amdgcn_rcpf(1.0f + p);
}
__device__ __forceinline__ short f2bf(float x) {
    __hip_bfloat16 h = __float2bfloat16(x);
    return *reinterpret_cast<short*>(&h);
}
__device__ __forceinline__ float bf2f(unsigned short s) {
    return __uint_as_float(((unsigned)s) << 16);
}
__device__ __forceinline__ unsigned pack_bf16(float a, float b) {
    unsigned ua = (unsigned)(unsigned short)f2bf(a);
    unsigned ub = (unsigned)(unsigned short)f2bf(b);
    return ua | (ub << 16);
}

// ---------------------------------------------------------------------------
// R9: FUSED scan -> own-attention kernel. One wave per (f, bblk=16 batches).
// Phase 1: verbatim R3 zero-exchange GRU scan (hs stores + q_s). The scan is
// LATENCY-pinned (~150us regardless of wave count, R8 launch-0 measurement),
// so the wave then runs phase 2 itself: wtilde to LDS (wtil tensor DELETED),
// then per-batch v3 online-softmax attention over its OWN hs rows (L2/L3
// dirty-hot, 256 KB/wave) -> emb. Removes both attn2 dispatches; keeps the
// sequential-scan count at the memory-minimum of 2 (FC=38).
// ---------------------------------------------------------------------------
__global__ __launch_bounds__(64) void gru_attn_kernel(
    const float* __restrict__ x, const float* __restrict__ w_ih,
    const float* __restrict__ w_hh, const float* __restrict__ b_ih,
    const float* __restrict__ b_hh, const float* __restrict__ Wt,
    const float* __restrict__ Wx, const float* __restrict__ rate,
    int f_base, __hip_bfloat16* __restrict__ hs, float* __restrict__ emb)
{
    const int f_loc = blockIdx.y;
    const int f     = f_base + f_loc;
    const int b0    = blockIdx.x * 16;
    const int lane  = threadIdx.x;
    const int c     = lane & 15;
    const int q     = lane >> 4;

    __shared__ float x_lds[TT][16];
    __shared__ float wt_s[64][8];
    __shared__ float wx_s[64][8];
    __shared__ short hx[16][72];
    __shared__ float q_s[16][8];
    __shared__ float wt_til[16][68];   // wtilde, LDS-only (was global wtil)

    for (int i = lane; i < TT * 16; i += 64) {
        int t = i >> 4, b = i & 15;
        x_lds[t][b] = x[((size_t)t * BBATCH + b0 + b) * FFEAT + f];
    }
    for (int i = lane; i < 512; i += 64) {
        ((float*)wt_s)[i] = Wt[(size_t)f * 512 + i];
        ((float*)wx_s)[i] = Wx[(size_t)f * 512 + i];
    }
    __syncthreads();

    // ---- Phase 1: verbatim R3 scan ----
    bf16x8 afr[12][2];
    {
        const float* whh_f = w_hh + (size_t)f * 192 * 64;
        #pragma unroll
        for (int nt = 0; nt < 12; ++nt) {
            int gate = nt >> 2, tt = nt & 3;
            int urow = (c >> 2) * 8 + (tt & 1) * 4 + (c & 3) + (tt >> 1) * 32;
            const float* row = whh_f + (size_t)(gate * 64 + urow) * 64;
            #pragma unroll
            for (int kq = 0; kq < 2; ++kq) {
                bf16x8 fr;
                #pragma unroll
                for (int j = 0; j < 8; ++j) fr[j] = f2bf(row[kq * 32 + q * 8 + j]);
                afr[nt][kq] = fr;
            }
        }
    }
    float wr[4][4], wz[4][4], wn[4][4], bnx[4][4];
    f32x4 biasv[12];
    #pragma unroll
    for (int tt = 0; tt < 4; ++tt) {
        #pragma unroll
        for (int r = 0; r < 4; ++r) {
            int u = q * 8 + (tt & 1) * 4 + r + (tt >> 1) * 32;
            wr[tt][r]  = w_ih[f*192 + u];
            wz[tt][r]  = w_ih[f*192 + 64 + u];
            wn[tt][r]  = w_ih[f*192 + 128 + u];
            bnx[tt][r] = b_ih[f*192 + 128 + u];
            biasv[tt][r]     = b_ih[f*192 + u]      + b_hh[f*192 + u];
            biasv[4 + tt][r] = b_ih[f*192 + 64 + u] + b_hh[f*192 + 64 + u];
            biasv[8 + tt][r] = b_hh[f*192 + 128 + u];
        }
    }

    float hprev[4][4];
    #pragma unroll
    for (int tt = 0; tt < 4; ++tt)
        #pragma unroll
        for (int r = 0; r < 4; ++r) hprev[tt][r] = 0.f;

    bf16x8 hb0 = {0,0,0,0,0,0,0,0};
    bf16x8 hb1 = {0,0,0,0,0,0,0,0};

    short* hs_b = (short*)hs + ((size_t)f_loc * BBATCH + b0 + c) * TT * HDIM;

    for (int t = 0; t < TT; ++t) {
        f32x4 acc[12];
        #pragma unroll
        for (int nt = 0; nt < 12; ++nt) {
            f32x4 a = __builtin_amdgcn_mfma_f32_16x16x32_bf16(afr[nt][0], hb0, biasv[nt], 0, 0, 0);
            acc[nt]  = __builtin_amdgcn_mfma_f32_16x16x32_bf16(afr[nt][1], hb1, a, 0, 0, 0);
        }

        float xv = x_lds[t][c];
        float hn4[4][4];
        #pragma unroll
        for (int tt = 0; tt < 4; ++tt) {
            #pragma unroll
            for (int r = 0; r < 4; ++r) {
                float R  = fmaf(xv, wr[tt][r], acc[tt][r]);
                float Z  = fmaf(xv, wz[tt][r], acc[4 + tt][r]);
                float NX = fmaf(xv, wn[tt][r], bnx[tt][r]);
                float rg = fast_sigmoid(R);
                float zg = fast_sigmoid(Z);
                float ng = fast_tanh(fmaf(rg, acc[8 + tt][r], NX));
                float hn = fmaf(zg, hprev[tt][r] - ng, ng);
                hprev[tt][r] = hn;
                hn4[tt][r] = hn;
            }
        }
        {
            union { int4 i; bf16x8 v; } u0, u1;
            u0.i.x = pack_bf16(hn4[0][0], hn4[0][1]);
            u0.i.y = pack_bf16(hn4[0][2], hn4[0][3]);
            u0.i.z = pack_bf16(hn4[1][0], hn4[1][1]);
            u0.i.w = pack_bf16(hn4[1][2], hn4[1][3]);
            u1.i.x = pack_bf16(hn4[2][0], hn4[2][1]);
            u1.i.y = pack_bf16(hn4[2][2], hn4[2][3]);
            u1.i.z = pack_bf16(hn4[3][0], hn4[3][1]);
            u1.i.w = pack_bf16(hn4[3][2], hn4[3][3]);
            hb0 = u0.v; hb1 = u1.v;
        }
        short* dst = hs_b + (size_t)t * HDIM + q * 8;
        *(bf16x8*)dst = hb0;
        *(bf16x8*)(dst + 32) = hb1;
    }

    *(bf16x8*)&hx[c][q * 8]      = hb0;
    *(bf16x8*)&hx[c][32 + q * 8] = hb1;

    #pragma unroll
    for (int rr = 0; rr < 2; ++rr) {
        int role = rr * 64 + lane;
        int b = role >> 3, a = role & 7;
        float s = 0.f;
        #pragma unroll 8
        for (int j = 0; j < 64; ++j)
            s = fmaf(bf2f((unsigned short)hx[b][j]), wt_s[j][a], s);
        q_s[b][a] = s;
    }
    // wtilde into LDS (same math as R3's wtil, minus the global round-trip)
    {
        int b = lane >> 2, jb = (lane & 3) * 16;
        float qreg[8];
        #pragma unroll
        for (int a = 0; a < 8; ++a) qreg[a] = q_s[b][a];
        #pragma unroll
        for (int j4 = 0; j4 < 4; ++j4) {
            float4 v;
            #pragma unroll
            for (int jj = 0; jj < 4; ++jj) {
                int j = jb + j4 * 4 + jj;
                float s = 0.f;
                #pragma unroll
                for (int a = 0; a < 8; ++a) s = fmaf(wx_s[j][a], qreg[a], s);
                (&v.x)[jj] = s;
            }
            *(float4*)&wt_til[b][jb + j4 * 4] = v;
        }
    }
    // drain hs stores + make wt_til visible to all lanes
    __syncthreads();

    // ---- Phase 2: per-batch v3 online-softmax attention over OWN hs ----
    const float rs = fast_sigmoid(rate[f]);
    const int g  = lane >> 3;   // row-group
    const int ii = lane & 7;    // unit-slice

    for (int bb = 0; bb < 16; ++bb) {
        float wv[8];
        {
            float4 a = *(const float4*)&wt_til[bb][8 * ii];
            float4 c2 = *(const float4*)&wt_til[bb][8 * ii + 4];
            wv[0]=a.x; wv[1]=a.y; wv[2]=a.z; wv[3]=a.w;
            wv[4]=c2.x; wv[5]=c2.y; wv[6]=c2.z; wv[7]=c2.w;
        }
        const uint4* basev = (const uint4*)((const short*)hs +
                              ((size_t)f_loc * BBATCH + b0 + bb) * TT * HDIM);

        float m = -1.0e30f, s = 0.f;
        float o[8];
        #pragma unroll
        for (int j = 0; j < 8; ++j) o[j] = 0.f;

        #pragma unroll 4
        for (int it = 0; it < 16; ++it) {
            const int t = it * 8 + g;
            uint4 U = basev[t * 8 + ii];
            float h[8];
            h[0] = __uint_as_float(U.x << 16); h[1] = __uint_as_float(U.x & 0xffff0000u);
            h[2] = __uint_as_float(U.y << 16); h[3] = __uint_as_float(U.y & 0xffff0000u);
            h[4] = __uint_as_float(U.z << 16); h[5] = __uint_as_float(U.z & 0xffff0000u);
            h[6] = __uint_as_float(U.w << 16); h[7] = __uint_as_float(U.w & 0xffff0000u);
            float dp = 0.f;
            #pragma unroll
            for (int j = 0; j < 8; ++j) dp = fmaf(h[j], wv[j], dp);
            dp += __shfl_xor(dp, 1, 64);
            dp += __shfl_xor(dp, 2, 64);
            dp += __shfl_xor(dp, 4, 64);
            float sig = fast_sigmoid(dp);
            float den = rs * (__logf(2.72f + (1.0f - sig)) * (float)(TT - t));
            float e = fmaxf(sig / den, 0.0f);
            float nm = fmaxf(m, e);
            float sc = __builtin_amdgcn_exp2f((m - nm) * LOG2E);
            float p  = __builtin_amdgcn_exp2f((e - nm) * LOG2E);
            s = fmaf(s, sc, p);
            #pragma unroll
            for (int j = 0; j < 8; ++j) o[j] = fmaf(o[j], sc, p * h[j]);
            m = nm;
        }
        #pragma unroll
        for (int k = 8; k <= 32; k <<= 1) {
            float om = __shfl_xor(m, k, 64);
            float os = __shfl_xor(s, k, 64);
            float nm = fmaxf(m, om);
            float sa = __builtin_amdgcn_exp2f((m - nm) * LOG2E);
            float sb = __builtin_amdgcn_exp2f((om - nm) * LOG2E);
            s = s * sa + os * sb;
            #pragma unroll
            for (int j = 0; j < 8; ++j) {
                float oo = __shfl_xor(o[j], k, 64);
                o[j] = o[j] * sa + oo * sb;
            }
            m = nm;
        }
        if (g == 0) {
            float inv = __builtin_amdgcn_rcpf(s);
            float4 v0, v1;
            v0.x = o[0]*inv; v0.y = o[1]*inv; v0.z = o[2]*inv; v0.w = o[3]*inv;
            v1.x = o[4]*inv; v1.y = o[5]*inv; v1.z = o[6]*inv; v1.w = o[7]*inv;
            float* dst = &emb[((size_t)(b0 + bb) * FFEAT + f) * HDIM + 8 * ii];
            *(float4*)dst       = v0;
            *(float4*)(dst + 4) = v1;
        }
    }
}

// ---------------------------------------------------------------------------
// Tail: tiled GEMM + MHA core + final head (proven split kernels, unchanged).
// ---------------------------------------------------------------------------
struct GemmP {
    const float* X;
    const float* W[3];
    const float* B[3];
    const float* R;
    float* Y[3];
    int K;
    int Nfull;
    int act;
};

__global__ __launch_bounds__(256) void gemm_kernel(GemmP A)
{
    __shared__ float xs[64][65];
    __shared__ float ws[64][68];

    const int tid = threadIdx.x;
    const int tx  = tid & 15;
    const int ty  = tid >> 4;
    const int m0  = blockIdx.x * 64;
    const int n0  = blockIdx.y * 64;
    const int z   = blockIdx.z;

    const float* W = A.W[z];
    const float* Bv = A.B[z];
    float* Y = A.Y[z];
    const int K = A.K, Nfull = A.Nfull;

    float acc[4][4];
    #pragma unroll
    for (int i = 0; i < 4; ++i)
        #pragma unroll
        for (int j = 0; j < 4; ++j) acc[i][j] = 0.f;

    for (int kc = 0; kc < K; kc += 64) {
        for (int s = tid; s < 1024; s += 256) {
            int row = s >> 4, c4 = s & 15;
            float4 xv = *(const float4*)&A.X[(size_t)(m0 + row) * K + kc + 4*c4];
            xs[row][4*c4+0] = xv.x; xs[row][4*c4+1] = xv.y;
            xs[row][4*c4+2] = xv.z; xs[row][4*c4+3] = xv.w;
            float4 wv = *(const float4*)&W[(size_t)(kc + row) * Nfull + n0 + 4*c4];
            *(float4*)&ws[row][4*c4] = wv;
        }
        __syncthreads();
        #pragma unroll 16
        for (int k = 0; k < 64; ++k) {
            float a0 = xs[4*ty+0][k], a1 = xs[4*ty+1][k];
            float a2 = xs[4*ty+2][k], a3 = xs[4*ty+3][k];
            float4 wv = *(const float4*)&ws[k][4*tx];
            #pragma unroll
            for (int j = 0; j < 4; ++j) {
                float wj = (&wv.x)[j];
                acc[0][j] = fmaf(a0, wj, acc[0][j]);
                acc[1][j] = fmaf(a1, wj, acc[1][j]);
                acc[2][j] = fmaf(a2, wj, acc[2][j]);
                acc[3][j] = fmaf(a3, wj, acc[3][j]);
            }
        }
        __syncthreads();
    }

    float4 bias = *(const float4*)&Bv[n0 + 4*tx];
    #pragma unroll
    for (int i = 0; i < 4; ++i) {
        int row = m0 + 4*ty + i;
        float4 v;
        v.x = acc[i][0] + bias.x; v.y = acc[i][1] + bias.y;
        v.z = acc[i][2] + bias.z; v.w = acc[i][3] + bias.w;
        if (A.act) {
            v.x = fmaxf(v.x, 0.f); v.y = fmaxf(v.y, 0.f);
            v.z = fmaxf(v.z, 0.f); v.w = fmaxf(v.w, 0.f);
        }
        if (A.R) {
            float4 r4 = *(const float4*)&A.R[(size_t)row * Nfull + n0 + 4*tx];
            v.x += r4.x; v.y += r4.y; v.z += r4.z; v.w += r4.w;
        }
        *(float4*)&Y[(size_t)row * Nfull + n0 + 4*tx] = v;
    }
}

__global__ __launch_bounds__(256) void mha_core_kernel(
    const float* __restrict__ q, const float* __restrict__ k,
    const float* __restrict__ v, float* __restrict__ ctx)
{
    const int b  = blockIdx.x;
    const int hh = blockIdx.y;
    const int tid = threadIdx.x;

    __shared__ float qs[FFEAT][17];
    __shared__ float ks[FFEAT][17];
    __shared__ float vs[FFEAT][17];
    __shared__ float ps[FFEAT][77];

    for (int idx = tid; idx < FFEAT * DKH; idx += 256) {
        int i = idx >> 4, c = idx & 15;
        size_t g = ((size_t)b * FFEAT + i) * HDIM + hh * DKH + c;
        qs[i][c] = q[g]; ks[i][c] = k[g]; vs[i][c] = v[g];
    }
    __syncthreads();

    for (int idx = tid; idx < FFEAT * FFEAT; idx += 256) {
        int i = idx / FFEAT, j = idx % FFEAT;
        float acc = 0.f;
        #pragma unroll
        for (int c = 0; c < DKH; ++c) acc = fmaf(qs[i][c], ks[j][c], acc);
        ps[i][j] = acc * 0.25f;
    }
    __syncthreads();

    if (tid < FFEAT) {
        float mm = ps[tid][0];
        #pragma unroll 4
        for (int j = 1; j < FFEAT; ++j) mm = fmaxf(mm, ps[tid][j]);
        float ss = 0.f;
        #pragma unroll 4
        for (int j = 0; j < FFEAT; ++j) {
            float pv = __builtin_amdgcn_exp2f((ps[tid][j] - mm) * LOG2E);
            ps[tid][j] = pv; ss += pv;
        }
        float inv = 1.0f / ss;
        #pragma unroll 4
        for (int j = 0; j < FFEAT; ++j) ps[tid][j] *= inv;
    }
    __syncthreads();

    for (int idx = tid; idx < FFEAT * DKH; idx += 256) {
        int i = idx >> 4, c = idx & 15;
        float acc = 0.f;
        #pragma unroll 4
        for (int j = 0; j < FFEAT; ++j) acc = fmaf(ps[i][j], vs[j][c], acc);
        ctx[((size_t)b * FFEAT + i) * HDIM + hh * DKH + c] = acc;
    }
}

__global__ __launch_bounds__(128) void final_kernel(
    const float* __restrict__ ctx3, const float* __restrict__ fk,
    const float* __restrict__ fv,
    const float* __restrict__ faq, const float* __restrict__ fabq,
    const float* __restrict__ o0w, const float* __restrict__ o0b,
    const float* __restrict__ o1w, const float* __restrict__ o1b,
    float* __restrict__ out)
{
    const int b = blockIdx.x;
    const int tid = threadIdx.x;

    __shared__ float last[HDIM];
    __shared__ float fqs[HDIM];
    __shared__ float sm[FFEAT];
    __shared__ float vv[HDIM];
    __shared__ float hh[HDIM];
    __shared__ float redm[2], redp[2];

    if (tid < HDIM) last[tid] = ctx3[((size_t)b * FFEAT + FFEAT - 1) * HDIM + tid];
    __syncthreads();
    if (tid < HDIM) {
        float acc = fabq[tid];
        #pragma unroll 8
        for (int j = 0; j < HDIM; ++j) acc = fmaf(last[j], faq[j * HDIM + tid], acc);
        fqs[tid] = acc;
    }
    __syncthreads();

    float e = -3.0e38f;
    if (tid < FFEAT) {
        const float4* kr = (const float4*)&fk[((size_t)b * FFEAT + tid) * HDIM];
        float acc = 0.f;
        #pragma unroll
        for (int c4 = 0; c4 < 16; ++c4) {
            float4 kv = kr[c4];
            acc = fmaf(kv.x, fqs[4*c4+0], acc);
            acc = fmaf(kv.y, fqs[4*c4+1], acc);
            acc = fmaf(kv.z, fqs[4*c4+2], acc);
            acc = fmaf(kv.w, fqs[4*c4+3], acc);
        }
        e = acc;
    }
    float m = e;
    #pragma unroll
    for (int off = 32; off > 0; off >>= 1) m = fmaxf(m, __shfl_xor(m, off, 64));
    if ((tid & 63) == 0) redm[tid >> 6] = m;
    __syncthreads();
    m = fmaxf(redm[0], redm[1]);
    float p = (tid < FFEAT) ? __builtin_amdgcn_exp2f((e - m) * LOG2E) : 0.f;
    float s = p;
    #pragma unroll
    for (int off = 32; off > 0; off >>= 1) s += __shfl_xor(s, off, 64);
    if ((tid & 63) == 0) redp[tid >> 6] = s;
    __syncthreads();
    s = redp[0] + redp[1];
    if (tid < FFEAT) sm[tid] = p / s;
    __syncthreads();

    if (tid < HDIM) {
        float acc = 0.f;
        for (int ff = 0; ff < FFEAT; ++ff)
            acc = fmaf(sm[ff], fv[((size_t)b * FFEAT + ff) * HDIM + tid], acc);
        vv[tid] = acc;
    }
    __syncthreads();
    if (tid < HDIM) {
        float acc = o0b[tid];
        #pragma unroll 8
        for (int j = 0; j < HDIM; ++j) acc = fmaf(vv[j], o0w[j * HDIM + tid], acc);
        hh[tid] = fmaxf(acc, 0.f);
    }
    __syncthreads();
    if (tid < 64) {
        float t = hh[tid] * o1w[tid];
        #pragma unroll
        for (int off = 32; off > 0; off >>= 1) t += __shfl_xor(t, off, 64);
        if (tid == 0) out[b] = fast_sigmoid(t + o1b[0]);
    }
}

__global__ void ws_report_kernel(float* out, int n, float ws_mib) {
    int i = blockIdx.x * blockDim.x + threadIdx.x;
    if (i < n) out[i] = ws_mib;
}

extern "C" void kernel_launch(void* const* d_in, const int* in_sizes, int n_in,
                              void* d_out, int out_size, void* d_ws, size_t ws_size,
                              hipStream_t stream)
{
    const float* x     = (const float*)d_in[0];
    const float* w_ih  = (const float*)d_in[1];
    const float* w_hh  = (const float*)d_in[2];
    const float* b_ih  = (const float*)d_in[3];
    const float* b_hh  = (const float*)d_in[4];
    const float* attWt = (const float*)d_in[5];
    const float* attWx = (const float*)d_in[6];
    const float* attRt = (const float*)d_in[7];
    const float* wq    = (const float*)d_in[8];
    const float* bq    = (const float*)d_in[9];
    const float* wk    = (const float*)d_in[10];
    const float* bk    = (const float*)d_in[11];
    const float* wv    = (const float*)d_in[12];
    const float* bv    = (const float*)d_in[13];
    const float* wo    = (const float*)d_in[14];
    const float* bo    = (const float*)d_in[15];
    const float* w1    = (const float*)d_in[16];
    const float* b1    = (const float*)d_in[17];
    const float* w2    = (const float*)d_in[18];
    const float* b2    = (const float*)d_in[19];
    const float* faq   = (const float*)d_in[20];
    const float* fabq  = (const float*)d_in[21];
    const float* fak   = (const float*)d_in[22];
    const float* fabk  = (const float*)d_in[23];
    const float* fav   = (const float*)d_in[24];
    const float* fabv  = (const float*)d_in[25];
    const float* o0w   = (const float*)d_in[26];
    const float* o0b   = (const float*)d_in[27];
    const float* o1w   = (const float*)d_in[28];
    const float* o1b   = (const float*)d_in[29];
    float* out = (float*)d_out;

    const size_t emb_bytes = (size_t)NROWS * HDIM * 4;   // 4.98 MB (wtil deleted)
    const size_t R64       = (size_t)NROWS * HDIM;
    const size_t tail_bytes = 12 * R64 * 4;              // 59.8 MB

    const int chunk_opts[5] = {38, 19, 4, 2, 1};
    int FC = 0;
    for (int i = 0; i < 5; ++i) {
        size_t hs_b = (size_t)chunk_opts[i] * BBATCH * TT * HDIM * 2;
        size_t scratch = hs_b > tail_bytes ? hs_b : tail_bytes;
        if (emb_bytes + scratch <= ws_size) { FC = chunk_opts[i]; break; }
    }
    if (FC == 0) {
        ws_report_kernel<<<dim3((out_size + 255) / 256), dim3(256), 0, stream>>>(
            out, out_size, (float)((double)ws_size / (1024.0 * 1024.0)));
        return;
    }

    float* emb  = (float*)d_ws;
    char*  scratch = (char*)d_ws + emb_bytes;
    __hip_bfloat16* hs = (__hip_bfloat16*)scratch;

    for (int f0 = 0; f0 < FFEAT; f0 += FC) {
        int fc = (FFEAT - f0 < FC) ? (FFEAT - f0) : FC;
        gru_attn_kernel<<<dim3(16, fc), dim3(64), 0, stream>>>(
            x, w_ih, w_hh, b_ih, b_hh, attWt, attWx, attRt, f0, hs, emb);
    }

    float* ts   = (float*)scratch;
    float* q    = ts;
    float* k    = ts + 1*R64;
    float* v    = ts + 2*R64;
    float* ctx  = ts + 3*R64;
    float* ctx2 = ts + 4*R64;
    float* hid  = ts + 5*R64;
    float* ctx3 = ts + 9*R64;
    float* fk   = ts + 10*R64;
    float* fv   = ts + 11*R64;

    const int MB = NROWS / 64;

    {
        GemmP A = { emb, {wq, wk, wv}, {bq, bk, bv}, nullptr, {q, k, v}, 64, 64, 0 };
        gemm_kernel<<<dim3(MB, 1, 3), dim3(256), 0, stream>>>(A);
    }
    mha_core_kernel<<<dim3(BBATCH, NHEAD), dim3(256), 0, stream>>>(q, k, v, ctx);
    {
        GemmP A = { ctx, {wo, nullptr, nullptr}, {bo, nullptr, nullptr}, emb,
                    {ctx2, nullptr, nullptr}, 64, 64, 0 };
        gemm_kernel<<<dim3(MB, 1, 1), dim3(256), 0, stream>>>(A);
    }
    {
        GemmP A = { ctx2, {w1, nullptr, nullptr}, {b1, nullptr, nullptr}, nullptr,
                    {hid, nullptr, nullptr}, 64, 256, 1 };
        gemm_kernel<<<dim3(MB, 4, 1), dim3(256), 0, stream>>>(A);
    }
    {
        GemmP A = { hid, {w2, nullptr, nullptr}, {b2, nullptr, nullptr}, ctx2,
                    {ctx3, nullptr, nullptr}, 256, 64, 0 };
        gemm_kernel<<<dim3(MB, 1, 1), dim3(256), 0, stream>>>(A);
    }
    {
        GemmP A = { ctx3, {fak, fav, nullptr}, {fabk, fabv, nullptr}, nullptr,
                    {fk, fv, nullptr}, 64, 64, 0 };
        gemm_kernel<<<dim3(MB, 1, 2), dim3(256), 0, stream>>>(A);
    }
    final_kernel<<<dim3(BBATCH), dim3(128), 0, stream>>>(
        ctx3, fk, fv, faq, fabq, o0w, o0b, o1w, o1b, out);
}

// Round 10
// 567.173 us; speedup vs baseline: 1.4444x; 1.1266x over previous
//
#include <hip/hip_runtime.h>
#include <hip/hip_bf16.h>
#include <cstdint>
#include <cstddef>

#define TT 128
#define BBATCH 256
#define FFEAT 76
#define HDIM 64
#define NHEAD 4
#define DKH 16
#define DFF1 256
#define AH1 8
#define NROWS (BBATCH * FFEAT)   // 19456

#define LOG2E 1.4426950408889634f

typedef __attribute__((ext_vector_type(8))) short bf16x8;
typedef __attribute__((ext_vector_type(4))) float f32x4;

__device__ __forceinline__ float fast_sigmoid(float v) {
    float p = __builtin_amdgcn_exp2f(-v * LOG2E);
    return __builtin_amdgcn_rcpf(1.0f + p);
}
__device__ __forceinline__ float fast_tanh(float v) {
    float p = __builtin_amdgcn_exp2f(v * (2.0f * LOG2E));
    return 1.0f - 2.0f * __builtin_amdgcn_rcpf(1.0f + p);
}
__device__ __forceinline__ short f2bf(float x) {
    __hip_bfloat16 h = __float2bfloat16(x);
    return *reinterpret_cast<short*>(&h);
}
__device__ __forceinline__ float bf2f(unsigned short s) {
    return __uint_as_float(((unsigned)s) << 16);
}
__device__ __forceinline__ unsigned pack_bf16(float a, float b) {
    unsigned ua = (unsigned)(unsigned short)f2bf(a);
    unsigned ub = (unsigned)(unsigned short)f2bf(b);
    return ua | (ub << 16);
}

// ---------------------------------------------------------------------------
// Kernel 1: ZERO-EXCHANGE GRU scan — VERBATIM R3 (proven 155us/38-feat).
// R10: no kernel change; the host now runs it as ONE full-width dispatch
// (1216 waves) when workspace allows (wtil/emb aliasing frees 5 MB), else
// the proven 2-chunk sequence. Tests latency-floor vs throughput law with
// zero downside.
// ---------------------------------------------------------------------------
__global__ __launch_bounds__(64) void gru_scan_kernel(
    const float* __restrict__ x, const float* __restrict__ w_ih,
    const float* __restrict__ w_hh, const float* __restrict__ b_ih,
    const float* __restrict__ b_hh, const float* __restrict__ Wt,
    const float* __restrict__ Wx, int f_base,
    __hip_bfloat16* __restrict__ hs, float* __restrict__ wtil)
{
    const int f_loc = blockIdx.y;
    const int f     = f_base + f_loc;
    const int b0    = blockIdx.x * 16;
    const int lane  = threadIdx.x;
    const int c     = lane & 15;
    const int q     = lane >> 4;

    __shared__ float x_lds[TT][16];
    __shared__ float wt_s[64][8];
    __shared__ float wx_s[64][8];
    __shared__ short hx[16][72];
    __shared__ float q_s[16][8];

    for (int i = lane; i < TT * 16; i += 64) {
        int t = i >> 4, b = i & 15;
        x_lds[t][b] = x[((size_t)t * BBATCH + b0 + b) * FFEAT + f];
    }
    for (int i = lane; i < 512; i += 64) {
        ((float*)wt_s)[i] = Wt[(size_t)f * 512 + i];
        ((float*)wx_s)[i] = Wx[(size_t)f * 512 + i];
    }
    __syncthreads();

    bf16x8 afr[12][2];
    {
        const float* whh_f = w_hh + (size_t)f * 192 * 64;
        #pragma unroll
        for (int nt = 0; nt < 12; ++nt) {
            int gate = nt >> 2, tt = nt & 3;
            int urow = (c >> 2) * 8 + (tt & 1) * 4 + (c & 3) + (tt >> 1) * 32;
            const float* row = whh_f + (size_t)(gate * 64 + urow) * 64;
            #pragma unroll
            for (int kq = 0; kq < 2; ++kq) {
                bf16x8 fr;
                #pragma unroll
                for (int j = 0; j < 8; ++j) fr[j] = f2bf(row[kq * 32 + q * 8 + j]);
                afr[nt][kq] = fr;
            }
        }
    }
    float wr[4][4], wz[4][4], wn[4][4], bnx[4][4];
    f32x4 biasv[12];
    #pragma unroll
    for (int tt = 0; tt < 4; ++tt) {
        #pragma unroll
        for (int r = 0; r < 4; ++r) {
            int u = q * 8 + (tt & 1) * 4 + r + (tt >> 1) * 32;
            wr[tt][r]  = w_ih[f*192 + u];
            wz[tt][r]  = w_ih[f*192 + 64 + u];
            wn[tt][r]  = w_ih[f*192 + 128 + u];
            bnx[tt][r] = b_ih[f*192 + 128 + u];
            biasv[tt][r]     = b_ih[f*192 + u]      + b_hh[f*192 + u];
            biasv[4 + tt][r] = b_ih[f*192 + 64 + u] + b_hh[f*192 + 64 + u];
            biasv[8 + tt][r] = b_hh[f*192 + 128 + u];
        }
    }

    float hprev[4][4];
    #pragma unroll
    for (int tt = 0; tt < 4; ++tt)
        #pragma unroll
        for (int r = 0; r < 4; ++r) hprev[tt][r] = 0.f;

    bf16x8 hb0 = {0,0,0,0,0,0,0,0};
    bf16x8 hb1 = {0,0,0,0,0,0,0,0};

    short* hs_b = (short*)hs + ((size_t)f_loc * BBATCH + b0 + c) * TT * HDIM;

    for (int t = 0; t < TT; ++t) {
        f32x4 acc[12];
        #pragma unroll
        for (int nt = 0; nt < 12; ++nt) {
            f32x4 a = __builtin_amdgcn_mfma_f32_16x16x32_bf16(afr[nt][0], hb0, biasv[nt], 0, 0, 0);
            acc[nt]  = __builtin_amdgcn_mfma_f32_16x16x32_bf16(afr[nt][1], hb1, a, 0, 0, 0);
        }

        float xv = x_lds[t][c];
        float hn4[4][4];
        #pragma unroll
        for (int tt = 0; tt < 4; ++tt) {
            #pragma unroll
            for (int r = 0; r < 4; ++r) {
                float R  = fmaf(xv, wr[tt][r], acc[tt][r]);
                float Z  = fmaf(xv, wz[tt][r], acc[4 + tt][r]);
                float NX = fmaf(xv, wn[tt][r], bnx[tt][r]);
                float rg = fast_sigmoid(R);
                float zg = fast_sigmoid(Z);
                float ng = fast_tanh(fmaf(rg, acc[8 + tt][r], NX));
                float hn = fmaf(zg, hprev[tt][r] - ng, ng);
                hprev[tt][r] = hn;
                hn4[tt][r] = hn;
            }
        }
        {
            union { int4 i; bf16x8 v; } u0, u1;
            u0.i.x = pack_bf16(hn4[0][0], hn4[0][1]);
            u0.i.y = pack_bf16(hn4[0][2], hn4[0][3]);
            u0.i.z = pack_bf16(hn4[1][0], hn4[1][1]);
            u0.i.w = pack_bf16(hn4[1][2], hn4[1][3]);
            u1.i.x = pack_bf16(hn4[2][0], hn4[2][1]);
            u1.i.y = pack_bf16(hn4[2][2], hn4[2][3]);
            u1.i.z = pack_bf16(hn4[3][0], hn4[3][1]);
            u1.i.w = pack_bf16(hn4[3][2], hn4[3][3]);
            hb0 = u0.v; hb1 = u1.v;
        }
        short* dst = hs_b + (size_t)t * HDIM + q * 8;
        *(bf16x8*)dst = hb0;
        *(bf16x8*)(dst + 32) = hb1;
    }

    *(bf16x8*)&hx[c][q * 8]      = hb0;
    *(bf16x8*)&hx[c][32 + q * 8] = hb1;

    #pragma unroll
    for (int rr = 0; rr < 2; ++rr) {
        int role = rr * 64 + lane;
        int b = role >> 3, a = role & 7;
        float s = 0.f;
        #pragma unroll 8
        for (int j = 0; j < 64; ++j)
            s = fmaf(bf2f((unsigned short)hx[b][j]), wt_s[j][a], s);
        q_s[b][a] = s;
    }
    {
        int b = lane >> 2, jb = (lane & 3) * 16;
        float qreg[8];
        #pragma unroll
        for (int a = 0; a < 8; ++a) qreg[a] = q_s[b][a];
        float* wt_out = wtil + ((size_t)(b0 + b) * FFEAT + f) * HDIM + jb;
        #pragma unroll
        for (int j4 = 0; j4 < 4; ++j4) {
            float4 v;
            #pragma unroll
            for (int jj = 0; jj < 4; ++jj) {
                int j = jb + j4 * 4 + jj;
                float s = 0.f;
                #pragma unroll
                for (int a = 0; a < 8; ++a) s = fmaf(wx_s[j][a], qreg[a], s);
                (&v.x)[jj] = s;
            }
            *(float4*)&wt_out[j4 * 4] = v;
        }
    }
}

// ---------------------------------------------------------------------------
// Kernel 2 v3: SINGLE-PASS online-softmax time attention (verbatim R3 math).
// R10: wtil/emb may ALIAS (block reads its wtilde row fully before writing
// the same emb row) — __restrict__ removed from those params.
// ---------------------------------------------------------------------------
__global__ __launch_bounds__(256) void attn2_kernel(
    const __hip_bfloat16* __restrict__ hs, const float* wtil,
    const float* __restrict__ rate, int f_base, float* emb)
{
    const int w     = threadIdx.x >> 6;
    const int lane  = threadIdx.x & 63;
    const int b     = blockIdx.x * 4 + w;
    const int f_loc = blockIdx.y;
    const int f     = f_base + f_loc;
    const int g     = lane >> 3;
    const int i     = lane & 7;

    float wv[8];
    {
        const float4* src = (const float4*)(wtil + ((size_t)b * FFEAT + f) * HDIM + 8 * i);
        float4 a = src[0], c2 = src[1];
        wv[0]=a.x; wv[1]=a.y; wv[2]=a.z; wv[3]=a.w;
        wv[4]=c2.x; wv[5]=c2.y; wv[6]=c2.z; wv[7]=c2.w;
    }
    const float rs = fast_sigmoid(rate[f]);
    const uint4* basev = (const uint4*)((const short*)hs +
                          ((size_t)f_loc * BBATCH + b) * TT * HDIM);

    float m = -1.0e30f, s = 0.f;
    float o[8];
    #pragma unroll
    for (int j = 0; j < 8; ++j) o[j] = 0.f;

    #pragma unroll 4
    for (int it = 0; it < 16; ++it) {
        const int t = it * 8 + g;
        uint4 U = basev[t * 8 + i];
        float h[8];
        h[0] = __uint_as_float(U.x << 16); h[1] = __uint_as_float(U.x & 0xffff0000u);
        h[2] = __uint_as_float(U.y << 16); h[3] = __uint_as_float(U.y & 0xffff0000u);
        h[4] = __uint_as_float(U.z << 16); h[5] = __uint_as_float(U.z & 0xffff0000u);
        h[6] = __uint_as_float(U.w << 16); h[7] = __uint_as_float(U.w & 0xffff0000u);
        float dp = 0.f;
        #pragma unroll
        for (int j = 0; j < 8; ++j) dp = fmaf(h[j], wv[j], dp);
        dp += __shfl_xor(dp, 1, 64);
        dp += __shfl_xor(dp, 2, 64);
        dp += __shfl_xor(dp, 4, 64);
        float sig = fast_sigmoid(dp);
        float den = rs * (__logf(2.72f + (1.0f - sig)) * (float)(TT - t));
        float e = fmaxf(sig / den, 0.0f);
        float nm = fmaxf(m, e);
        float sc = __builtin_amdgcn_exp2f((m - nm) * LOG2E);
        float p  = __builtin_amdgcn_exp2f((e - nm) * LOG2E);
        s = fmaf(s, sc, p);
        #pragma unroll
        for (int j = 0; j < 8; ++j) o[j] = fmaf(o[j], sc, p * h[j]);
        m = nm;
    }
    #pragma unroll
    for (int k = 8; k <= 32; k <<= 1) {
        float om = __shfl_xor(m, k, 64);
        float os = __shfl_xor(s, k, 64);
        float nm = fmaxf(m, om);
        float sa = __builtin_amdgcn_exp2f((m - nm) * LOG2E);
        float sb = __builtin_amdgcn_exp2f((om - nm) * LOG2E);
        s = s * sa + os * sb;
        #pragma unroll
        for (int j = 0; j < 8; ++j) {
            float oo = __shfl_xor(o[j], k, 64);
            o[j] = o[j] * sa + oo * sb;
        }
        m = nm;
    }
    if (g == 0) {
        float inv = __builtin_amdgcn_rcpf(s);
        float4 v0, v1;
        v0.x = o[0]*inv; v0.y = o[1]*inv; v0.z = o[2]*inv; v0.w = o[3]*inv;
        v1.x = o[4]*inv; v1.y = o[5]*inv; v1.z = o[6]*inv; v1.w = o[7]*inv;
        float* dst = &emb[((size_t)b * FFEAT + f) * HDIM + 8 * i];
        *(float4*)dst       = v0;
        *(float4*)(dst + 4) = v1;
    }
}

// ---------------------------------------------------------------------------
// Tail: tiled GEMM + MHA core + final head (proven split kernels, unchanged).
// ---------------------------------------------------------------------------
struct GemmP {
    const float* X;
    const float* W[3];
    const float* B[3];
    const float* R;
    float* Y[3];
    int K;
    int Nfull;
    int act;
};

__global__ __launch_bounds__(256) void gemm_kernel(GemmP A)
{
    __shared__ float xs[64][65];
    __shared__ float ws[64][68];

    const int tid = threadIdx.x;
    const int tx  = tid & 15;
    const int ty  = tid >> 4;
    const int m0  = blockIdx.x * 64;
    const int n0  = blockIdx.y * 64;
    const int z   = blockIdx.z;

    const float* W = A.W[z];
    const float* Bv = A.B[z];
    float* Y = A.Y[z];
    const int K = A.K, Nfull = A.Nfull;

    float acc[4][4];
    #pragma unroll
    for (int i = 0; i < 4; ++i)
        #pragma unroll
        for (int j = 0; j < 4; ++j) acc[i][j] = 0.f;

    for (int kc = 0; kc < K; kc += 64) {
        for (int s = tid; s < 1024; s += 256) {
            int row = s >> 4, c4 = s & 15;
            float4 xv = *(const float4*)&A.X[(size_t)(m0 + row) * K + kc + 4*c4];
            xs[row][4*c4+0] = xv.x; xs[row][4*c4+1] = xv.y;
            xs[row][4*c4+2] = xv.z; xs[row][4*c4+3] = xv.w;
            float4 wv = *(const float4*)&W[(size_t)(kc + row) * Nfull + n0 + 4*c4];
            *(float4*)&ws[row][4*c4] = wv;
        }
        __syncthreads();
        #pragma unroll 16
        for (int k = 0; k < 64; ++k) {
            float a0 = xs[4*ty+0][k], a1 = xs[4*ty+1][k];
            float a2 = xs[4*ty+2][k], a3 = xs[4*ty+3][k];
            float4 wv = *(const float4*)&ws[k][4*tx];
            #pragma unroll
            for (int j = 0; j < 4; ++j) {
                float wj = (&wv.x)[j];
                acc[0][j] = fmaf(a0, wj, acc[0][j]);
                acc[1][j] = fmaf(a1, wj, acc[1][j]);
                acc[2][j] = fmaf(a2, wj, acc[2][j]);
                acc[3][j] = fmaf(a3, wj, acc[3][j]);
            }
        }
        __syncthreads();
    }

    float4 bias = *(const float4*)&Bv[n0 + 4*tx];
    #pragma unroll
    for (int i = 0; i < 4; ++i) {
        int row = m0 + 4*ty + i;
        float4 v;
        v.x = acc[i][0] + bias.x; v.y = acc[i][1] + bias.y;
        v.z = acc[i][2] + bias.z; v.w = acc[i][3] + bias.w;
        if (A.act) {
            v.x = fmaxf(v.x, 0.f); v.y = fmaxf(v.y, 0.f);
            v.z = fmaxf(v.z, 0.f); v.w = fmaxf(v.w, 0.f);
        }
        if (A.R) {
            float4 r4 = *(const float4*)&A.R[(size_t)row * Nfull + n0 + 4*tx];
            v.x += r4.x; v.y += r4.y; v.z += r4.z; v.w += r4.w;
        }
        *(float4*)&Y[(size_t)row * Nfull + n0 + 4*tx] = v;
    }
}

__global__ __launch_bounds__(256) void mha_core_kernel(
    const float* __restrict__ q, const float* __restrict__ k,
    const float* __restrict__ v, float* __restrict__ ctx)
{
    const int b  = blockIdx.x;
    const int hh = blockIdx.y;
    const int tid = threadIdx.x;

    __shared__ float qs[FFEAT][17];
    __shared__ float ks[FFEAT][17];
    __shared__ float vs[FFEAT][17];
    __shared__ float ps[FFEAT][77];

    for (int idx = tid; idx < FFEAT * DKH; idx += 256) {
        int i = idx >> 4, c = idx & 15;
        size_t g = ((size_t)b * FFEAT + i) * HDIM + hh * DKH + c;
        qs[i][c] = q[g]; ks[i][c] = k[g]; vs[i][c] = v[g];
    }
    __syncthreads();

    for (int idx = tid; idx < FFEAT * FFEAT; idx += 256) {
        int i = idx / FFEAT, j = idx % FFEAT;
        float acc = 0.f;
        #pragma unroll
        for (int c = 0; c < DKH; ++c) acc = fmaf(qs[i][c], ks[j][c], acc);
        ps[i][j] = acc * 0.25f;
    }
    __syncthreads();

    if (tid < FFEAT) {
        float mm = ps[tid][0];
        #pragma unroll 4
        for (int j = 1; j < FFEAT; ++j) mm = fmaxf(mm, ps[tid][j]);
        float ss = 0.f;
        #pragma unroll 4
        for (int j = 0; j < FFEAT; ++j) {
            float pv = __builtin_amdgcn_exp2f((ps[tid][j] - mm) * LOG2E);
            ps[tid][j] = pv; ss += pv;
        }
        float inv = 1.0f / ss;
        #pragma unroll 4
        for (int j = 0; j < FFEAT; ++j) ps[tid][j] *= inv;
    }
    __syncthreads();

    for (int idx = tid; idx < FFEAT * DKH; idx += 256) {
        int i = idx >> 4, c = idx & 15;
        float acc = 0.f;
        #pragma unroll 4
        for (int j = 0; j < FFEAT; ++j) acc = fmaf(ps[i][j], vs[j][c], acc);
        ctx[((size_t)b * FFEAT + i) * HDIM + hh * DKH + c] = acc;
    }
}

__global__ __launch_bounds__(128) void final_kernel(
    const float* __restrict__ ctx3, const float* __restrict__ fk,
    const float* __restrict__ fv,
    const float* __restrict__ faq, const float* __restrict__ fabq,
    const float* __restrict__ o0w, const float* __restrict__ o0b,
    const float* __restrict__ o1w, const float* __restrict__ o1b,
    float* __restrict__ out)
{
    const int b = blockIdx.x;
    const int tid = threadIdx.x;

    __shared__ float last[HDIM];
    __shared__ float fqs[HDIM];
    __shared__ float sm[FFEAT];
    __shared__ float vv[HDIM];
    __shared__ float hh[HDIM];
    __shared__ float redm[2], redp[2];

    if (tid < HDIM) last[tid] = ctx3[((size_t)b * FFEAT + FFEAT - 1) * HDIM + tid];
    __syncthreads();
    if (tid < HDIM) {
        float acc = fabq[tid];
        #pragma unroll 8
        for (int j = 0; j < HDIM; ++j) acc = fmaf(last[j], faq[j * HDIM + tid], acc);
        fqs[tid] = acc;
    }
    __syncthreads();

    float e = -3.0e38f;
    if (tid < FFEAT) {
        const float4* kr = (const float4*)&fk[((size_t)b * FFEAT + tid) * HDIM];
        float acc = 0.f;
        #pragma unroll
        for (int c4 = 0; c4 < 16; ++c4) {
            float4 kv = kr[c4];
            acc = fmaf(kv.x, fqs[4*c4+0], acc);
            acc = fmaf(kv.y, fqs[4*c4+1], acc);
            acc = fmaf(kv.z, fqs[4*c4+2], acc);
            acc = fmaf(kv.w, fqs[4*c4+3], acc);
        }
        e = acc;
    }
    float m = e;
    #pragma unroll
    for (int off = 32; off > 0; off >>= 1) m = fmaxf(m, __shfl_xor(m, off, 64));
    if ((tid & 63) == 0) redm[tid >> 6] = m;
    __syncthreads();
    m = fmaxf(redm[0], redm[1]);
    float p = (tid < FFEAT) ? __builtin_amdgcn_exp2f((e - m) * LOG2E) : 0.f;
    float s = p;
    #pragma unroll
    for (int off = 32; off > 0; off >>= 1) s += __shfl_xor(s, off, 64);
    if ((tid & 63) == 0) redp[tid >> 6] = s;
    __syncthreads();
    s = redp[0] + redp[1];
    if (tid < FFEAT) sm[tid] = p / s;
    __syncthreads();

    if (tid < HDIM) {
        float acc = 0.f;
        for (int ff = 0; ff < FFEAT; ++ff)
            acc = fmaf(sm[ff], fv[((size_t)b * FFEAT + ff) * HDIM + tid], acc);
        vv[tid] = acc;
    }
    __syncthreads();
    if (tid < HDIM) {
        float acc = o0b[tid];
        #pragma unroll 8
        for (int j = 0; j < HDIM; ++j) acc = fmaf(vv[j], o0w[j * HDIM + tid], acc);
        hh[tid] = fmaxf(acc, 0.f);
    }
    __syncthreads();
    if (tid < 64) {
        float t = hh[tid] * o1w[tid];
        #pragma unroll
        for (int off = 32; off > 0; off >>= 1) t += __shfl_xor(t, off, 64);
        if (tid == 0) out[b] = fast_sigmoid(t + o1b[0]);
    }
}

__global__ void ws_report_kernel(float* out, int n, float ws_mib) {
    int i = blockIdx.x * blockDim.x + threadIdx.x;
    if (i < n) out[i] = ws_mib;
}

extern "C" void kernel_launch(void* const* d_in, const int* in_sizes, int n_in,
                              void* d_out, int out_size, void* d_ws, size_t ws_size,
                              hipStream_t stream)
{
    const float* x     = (const float*)d_in[0];
    const float* w_ih  = (const float*)d_in[1];
    const float* w_hh  = (const float*)d_in[2];
    const float* b_ih  = (const float*)d_in[3];
    const float* b_hh  = (const float*)d_in[4];
    const float* attWt = (const float*)d_in[5];
    const float* attWx = (const float*)d_in[6];
    const float* attRt = (const float*)d_in[7];
    const float* wq    = (const float*)d_in[8];
    const float* bq    = (const float*)d_in[9];
    const float* wk    = (const float*)d_in[10];
    const float* bk    = (const float*)d_in[11];
    const float* wv    = (const float*)d_in[12];
    const float* bv    = (const float*)d_in[13];
    const float* wo    = (const float*)d_in[14];
    const float* bo    = (const float*)d_in[15];
    const float* w1    = (const float*)d_in[16];
    const float* b1    = (const float*)d_in[17];
    const float* w2    = (const float*)d_in[18];
    const float* b2    = (const float*)d_in[19];
    const float* faq   = (const float*)d_in[20];
    const float* fabq  = (const float*)d_in[21];
    const float* fak   = (const float*)d_in[22];
    const float* fabk  = (const float*)d_in[23];
    const float* fav   = (const float*)d_in[24];
    const float* fabv  = (const float*)d_in[25];
    const float* o0w   = (const float*)d_in[26];
    const float* o0b   = (const float*)d_in[27];
    const float* o1w   = (const float*)d_in[28];
    const float* o1b   = (const float*)d_in[29];
    float* out = (float*)d_out;

    // wtil and emb SHARE one buffer (attn2 reads its wtilde row fully
    // before overwriting it with the emb row) -> 5 MB freed.
    const size_t embwtil_bytes = (size_t)NROWS * HDIM * 4;   // 4.98 MB
    const size_t R64           = (size_t)NROWS * HDIM;
    const size_t tail_bytes    = 12 * R64 * 4;               // 59.8 MB

    // Pick the largest feature chunk that fits: FC=76 -> ONE scan dispatch
    // (probes the latency-floor hypothesis; >= R3 either way), else the
    // proven 2-chunk path, else smaller.
    const int chunk_opts[6] = {76, 38, 19, 4, 2, 1};
    int FC = 0;
    for (int i = 0; i < 6; ++i) {
        size_t hs_b = (size_t)chunk_opts[i] * BBATCH * TT * HDIM * 2;
        size_t scratch = hs_b > tail_bytes ? hs_b : tail_bytes;
        if (embwtil_bytes + scratch <= ws_size) { FC = chunk_opts[i]; break; }
    }
    if (FC == 0) {
        ws_report_kernel<<<dim3((out_size + 255) / 256), dim3(256), 0, stream>>>(
            out, out_size, (float)((double)ws_size / (1024.0 * 1024.0)));
        return;
    }

    float* embwtil = (float*)d_ws;              // wtil during scan, emb after attn2
    char*  scratch = (char*)d_ws + embwtil_bytes;
    __hip_bfloat16* hs = (__hip_bfloat16*)scratch;

    for (int f0 = 0; f0 < FFEAT; f0 += FC) {
        int fc = (FFEAT - f0 < FC) ? (FFEAT - f0) : FC;
        gru_scan_kernel<<<dim3(16, fc), dim3(64), 0, stream>>>(
            x, w_ih, w_hh, b_ih, b_hh, attWt, attWx, f0, hs, embwtil);
        attn2_kernel<<<dim3(BBATCH / 4, fc), dim3(256), 0, stream>>>(
            hs, embwtil, attRt, f0, embwtil);
    }

    float* emb  = embwtil;
    float* ts   = (float*)scratch;
    float* q    = ts;
    float* k    = ts + 1*R64;
    float* v    = ts + 2*R64;
    float* ctx  = ts + 3*R64;
    float* ctx2 = ts + 4*R64;
    float* hid  = ts + 5*R64;
    float* ctx3 = ts + 9*R64;
    float* fk   = ts + 10*R64;
    float* fv   = ts + 11*R64;

    const int MB = NROWS / 64;

    {
        GemmP A = { emb, {wq, wk, wv}, {bq, bk, bv}, nullptr, {q, k, v}, 64, 64, 0 };
        gemm_kernel<<<dim3(MB, 1, 3), dim3(256), 0, stream>>>(A);
    }
    mha_core_kernel<<<dim3(BBATCH, NHEAD), dim3(256), 0, stream>>>(q, k, v, ctx);
    {
        GemmP A = { ctx, {wo, nullptr, nullptr}, {bo, nullptr, nullptr}, emb,
                    {ctx2, nullptr, nullptr}, 64, 64, 0 };
        gemm_kernel<<<dim3(MB, 1, 1), dim3(256), 0, stream>>>(A);
    }
    {
        GemmP A = { ctx2, {w1, nullptr, nullptr}, {b1, nullptr, nullptr}, nullptr,
                    {hid, nullptr, nullptr}, 64, 256, 1 };
        gemm_kernel<<<dim3(MB, 4, 1), dim3(256), 0, stream>>>(A);
    }
    {
        GemmP A = { hid, {w2, nullptr, nullptr}, {b2, nullptr, nullptr}, ctx2,
                    {ctx3, nullptr, nullptr}, 256, 64, 0 };
        gemm_kernel<<<dim3(MB, 1, 1), dim3(256), 0, stream>>>(A);
    }
    {
        GemmP A = { ctx3, {fak, fav, nullptr}, {fabk, fabv, nullptr}, nullptr,
                    {fk, fv, nullptr}, 64, 64, 0 };
        gemm_kernel<<<dim3(MB, 1, 2), dim3(256), 0, stream>>>(A);
    }
    final_kernel<<<dim3(BBATCH), dim3(128), 0, stream>>>(
        ctx3, fk, fv, faq, fabq, o0w, o0b, o1w, o1b, out);
}

// Round 11
// 564.697 us; speedup vs baseline: 1.4507x; 1.0044x over previous
//
#include <hip/hip_runtime.h>
#include <hip/hip_bf16.h>
#include <cstdint>
#include <cstddef>

#define TT 128
#define BBATCH 256
#define FFEAT 76
#define HDIM 64
#define NHEAD 4
#define DKH 16
#define DFF1 256
#define AH1 8
#define NROWS (BBATCH * FFEAT)   // 19456

#define LOG2E 1.4426950408889634f

typedef __attribute__((ext_vector_type(8))) short bf16x8;
typedef __attribute__((ext_vector_type(4))) float f32x4;

__device__ __forceinline__ float fast_sigmoid(float v) {
    float p = __builtin_amdgcn_exp2f(-v * LOG2E);
    return __builtin_amdgcn_rcpf(1.0f + p);
}
__device__ __forceinline__ float fast_tanh(float v) {
    float p = __builtin_amdgcn_exp2f(v * (2.0f * LOG2E));
    return 1.0f - 2.0f * __builtin_amdgcn_rcpf(1.0f + p);
}
__device__ __forceinline__ short f2bf(float x) {
    __hip_bfloat16 h = __float2bfloat16(x);
    return *reinterpret_cast<short*>(&h);
}
__device__ __forceinline__ float bf2f(unsigned short s) {
    return __uint_as_float(((unsigned)s) << 16);
}
__device__ __forceinline__ unsigned pack_bf16(float a, float b) {
    unsigned ua = (unsigned)(unsigned short)f2bf(a);
    unsigned ub = (unsigned)(unsigned short)f2bf(b);
    return ua | (ub << 16);
}

// ---------------------------------------------------------------------------
// Kernel 1: ZERO-EXCHANGE GRU scan — VERBATIM (proven 155us/38-feat).
// Session map: dispatch latency floor ~147us (<=608 waves) AND throughput
// ceiling ~3.9 wave-scans/us; the 2x608-wave config sits at both. Untouched.
// ---------------------------------------------------------------------------
__global__ __launch_bounds__(64) void gru_scan_kernel(
    const float* __restrict__ x, const float* __restrict__ w_ih,
    const float* __restrict__ w_hh, const float* __restrict__ b_ih,
    const float* __restrict__ b_hh, const float* __restrict__ Wt,
    const float* __restrict__ Wx, int f_base,
    __hip_bfloat16* __restrict__ hs, float* __restrict__ wtil)
{
    const int f_loc = blockIdx.y;
    const int f     = f_base + f_loc;
    const int b0    = blockIdx.x * 16;
    const int lane  = threadIdx.x;
    const int c     = lane & 15;
    const int q     = lane >> 4;

    __shared__ float x_lds[TT][16];
    __shared__ float wt_s[64][8];
    __shared__ float wx_s[64][8];
    __shared__ short hx[16][72];
    __shared__ float q_s[16][8];

    for (int i = lane; i < TT * 16; i += 64) {
        int t = i >> 4, b = i & 15;
        x_lds[t][b] = x[((size_t)t * BBATCH + b0 + b) * FFEAT + f];
    }
    for (int i = lane; i < 512; i += 64) {
        ((float*)wt_s)[i] = Wt[(size_t)f * 512 + i];
        ((float*)wx_s)[i] = Wx[(size_t)f * 512 + i];
    }
    __syncthreads();

    bf16x8 afr[12][2];
    {
        const float* whh_f = w_hh + (size_t)f * 192 * 64;
        #pragma unroll
        for (int nt = 0; nt < 12; ++nt) {
            int gate = nt >> 2, tt = nt & 3;
            int urow = (c >> 2) * 8 + (tt & 1) * 4 + (c & 3) + (tt >> 1) * 32;
            const float* row = whh_f + (size_t)(gate * 64 + urow) * 64;
            #pragma unroll
            for (int kq = 0; kq < 2; ++kq) {
                bf16x8 fr;
                #pragma unroll
                for (int j = 0; j < 8; ++j) fr[j] = f2bf(row[kq * 32 + q * 8 + j]);
                afr[nt][kq] = fr;
            }
        }
    }
    float wr[4][4], wz[4][4], wn[4][4], bnx[4][4];
    f32x4 biasv[12];
    #pragma unroll
    for (int tt = 0; tt < 4; ++tt) {
        #pragma unroll
        for (int r = 0; r < 4; ++r) {
            int u = q * 8 + (tt & 1) * 4 + r + (tt >> 1) * 32;
            wr[tt][r]  = w_ih[f*192 + u];
            wz[tt][r]  = w_ih[f*192 + 64 + u];
            wn[tt][r]  = w_ih[f*192 + 128 + u];
            bnx[tt][r] = b_ih[f*192 + 128 + u];
            biasv[tt][r]     = b_ih[f*192 + u]      + b_hh[f*192 + u];
            biasv[4 + tt][r] = b_ih[f*192 + 64 + u] + b_hh[f*192 + 64 + u];
            biasv[8 + tt][r] = b_hh[f*192 + 128 + u];
        }
    }

    float hprev[4][4];
    #pragma unroll
    for (int tt = 0; tt < 4; ++tt)
        #pragma unroll
        for (int r = 0; r < 4; ++r) hprev[tt][r] = 0.f;

    bf16x8 hb0 = {0,0,0,0,0,0,0,0};
    bf16x8 hb1 = {0,0,0,0,0,0,0,0};

    short* hs_b = (short*)hs + ((size_t)f_loc * BBATCH + b0 + c) * TT * HDIM;

    for (int t = 0; t < TT; ++t) {
        f32x4 acc[12];
        #pragma unroll
        for (int nt = 0; nt < 12; ++nt) {
            f32x4 a = __builtin_amdgcn_mfma_f32_16x16x32_bf16(afr[nt][0], hb0, biasv[nt], 0, 0, 0);
            acc[nt]  = __builtin_amdgcn_mfma_f32_16x16x32_bf16(afr[nt][1], hb1, a, 0, 0, 0);
        }

        float xv = x_lds[t][c];
        float hn4[4][4];
        #pragma unroll
        for (int tt = 0; tt < 4; ++tt) {
            #pragma unroll
            for (int r = 0; r < 4; ++r) {
                float R  = fmaf(xv, wr[tt][r], acc[tt][r]);
                float Z  = fmaf(xv, wz[tt][r], acc[4 + tt][r]);
                float NX = fmaf(xv, wn[tt][r], bnx[tt][r]);
                float rg = fast_sigmoid(R);
                float zg = fast_sigmoid(Z);
                float ng = fast_tanh(fmaf(rg, acc[8 + tt][r], NX));
                float hn = fmaf(zg, hprev[tt][r] - ng, ng);
                hprev[tt][r] = hn;
                hn4[tt][r] = hn;
            }
        }
        {
            union { int4 i; bf16x8 v; } u0, u1;
            u0.i.x = pack_bf16(hn4[0][0], hn4[0][1]);
            u0.i.y = pack_bf16(hn4[0][2], hn4[0][3]);
            u0.i.z = pack_bf16(hn4[1][0], hn4[1][1]);
            u0.i.w = pack_bf16(hn4[1][2], hn4[1][3]);
            u1.i.x = pack_bf16(hn4[2][0], hn4[2][1]);
            u1.i.y = pack_bf16(hn4[2][2], hn4[2][3]);
            u1.i.z = pack_bf16(hn4[3][0], hn4[3][1]);
            u1.i.w = pack_bf16(hn4[3][2], hn4[3][3]);
            hb0 = u0.v; hb1 = u1.v;
        }
        short* dst = hs_b + (size_t)t * HDIM + q * 8;
        *(bf16x8*)dst = hb0;
        *(bf16x8*)(dst + 32) = hb1;
    }

    *(bf16x8*)&hx[c][q * 8]      = hb0;
    *(bf16x8*)&hx[c][32 + q * 8] = hb1;

    #pragma unroll
    for (int rr = 0; rr < 2; ++rr) {
        int role = rr * 64 + lane;
        int b = role >> 3, a = role & 7;
        float s = 0.f;
        #pragma unroll 8
        for (int j = 0; j < 64; ++j)
            s = fmaf(bf2f((unsigned short)hx[b][j]), wt_s[j][a], s);
        q_s[b][a] = s;
    }
    {
        int b = lane >> 2, jb = (lane & 3) * 16;
        float qreg[8];
        #pragma unroll
        for (int a = 0; a < 8; ++a) qreg[a] = q_s[b][a];
        float* wt_out = wtil + ((size_t)(b0 + b) * FFEAT + f) * HDIM + jb;
        #pragma unroll
        for (int j4 = 0; j4 < 4; ++j4) {
            float4 v;
            #pragma unroll
            for (int jj = 0; jj < 4; ++jj) {
                int j = jb + j4 * 4 + jj;
                float s = 0.f;
                #pragma unroll
                for (int a = 0; a < 8; ++a) s = fmaf(wx_s[j][a], qreg[a], s);
                (&v.x)[jj] = s;
            }
            *(float4*)&wt_out[j4 * 4] = v;
        }
    }
}

// ---------------------------------------------------------------------------
// Kernel 2 v4 (R11): online-softmax time attention with FULL UPFRONT
// PREFETCH. All 16 row-loads per lane have static addresses and no
// dependence on the softmax state; with unroll-4 only ~4 were in flight and
// the dependent vmcnt waits exposed L3/HBM latency ~4x per wave. Now U[16]
// (64 VGPR) is issued before any math. Occupancy 8 -> ~4 waves/SIMD but
// in-flight loads/CU double and latency is exposed once. FP sequence is
// UNCHANGED -> bit-identical output. wtil/emb still alias (R10).
// ---------------------------------------------------------------------------
__global__ __launch_bounds__(256) void attn2_kernel(
    const __hip_bfloat16* __restrict__ hs, const float* wtil,
    const float* __restrict__ rate, int f_base, float* emb)
{
    const int w     = threadIdx.x >> 6;
    const int lane  = threadIdx.x & 63;
    const int b     = blockIdx.x * 4 + w;
    const int f_loc = blockIdx.y;
    const int f     = f_base + f_loc;
    const int g     = lane >> 3;
    const int i     = lane & 7;

    const uint4* basev = (const uint4*)((const short*)hs +
                          ((size_t)f_loc * BBATCH + b) * TT * HDIM);

    // ---- prefetch: issue ALL 16 loads before any dependent math ----
    uint4 U[16];
    #pragma unroll
    for (int it = 0; it < 16; ++it)
        U[it] = basev[(it * 8 + g) * 8 + i];

    float wv[8];
    {
        const float4* src = (const float4*)(wtil + ((size_t)b * FFEAT + f) * HDIM + 8 * i);
        float4 a = src[0], c2 = src[1];
        wv[0]=a.x; wv[1]=a.y; wv[2]=a.z; wv[3]=a.w;
        wv[4]=c2.x; wv[5]=c2.y; wv[6]=c2.z; wv[7]=c2.w;
    }
    const float rs = fast_sigmoid(rate[f]);

    float m = -1.0e30f, s = 0.f;
    float o[8];
    #pragma unroll
    for (int j = 0; j < 8; ++j) o[j] = 0.f;

    #pragma unroll
    for (int it = 0; it < 16; ++it) {
        const int t = it * 8 + g;
        uint4 Uv = U[it];
        float h[8];
        h[0] = __uint_as_float(Uv.x << 16); h[1] = __uint_as_float(Uv.x & 0xffff0000u);
        h[2] = __uint_as_float(Uv.y << 16); h[3] = __uint_as_float(Uv.y & 0xffff0000u);
        h[4] = __uint_as_float(Uv.z << 16); h[5] = __uint_as_float(Uv.z & 0xffff0000u);
        h[6] = __uint_as_float(Uv.w << 16); h[7] = __uint_as_float(Uv.w & 0xffff0000u);
        float dp = 0.f;
        #pragma unroll
        for (int j = 0; j < 8; ++j) dp = fmaf(h[j], wv[j], dp);
        dp += __shfl_xor(dp, 1, 64);
        dp += __shfl_xor(dp, 2, 64);
        dp += __shfl_xor(dp, 4, 64);
        float sig = fast_sigmoid(dp);
        float den = rs * (__logf(2.72f + (1.0f - sig)) * (float)(TT - t));
        float e = fmaxf(sig / den, 0.0f);
        float nm = fmaxf(m, e);
        float sc = __builtin_amdgcn_exp2f((m - nm) * LOG2E);
        float p  = __builtin_amdgcn_exp2f((e - nm) * LOG2E);
        s = fmaf(s, sc, p);
        #pragma unroll
        for (int j = 0; j < 8; ++j) o[j] = fmaf(o[j], sc, p * h[j]);
        m = nm;
    }
    #pragma unroll
    for (int k = 8; k <= 32; k <<= 1) {
        float om = __shfl_xor(m, k, 64);
        float os = __shfl_xor(s, k, 64);
        float nm = fmaxf(m, om);
        float sa = __builtin_amdgcn_exp2f((m - nm) * LOG2E);
        float sb = __builtin_amdgcn_exp2f((om - nm) * LOG2E);
        s = s * sa + os * sb;
        #pragma unroll
        for (int j = 0; j < 8; ++j) {
            float oo = __shfl_xor(o[j], k, 64);
            o[j] = o[j] * sa + oo * sb;
        }
        m = nm;
    }
    if (g == 0) {
        float inv = __builtin_amdgcn_rcpf(s);
        float4 v0, v1;
        v0.x = o[0]*inv; v0.y = o[1]*inv; v0.z = o[2]*inv; v0.w = o[3]*inv;
        v1.x = o[4]*inv; v1.y = o[5]*inv; v1.z = o[6]*inv; v1.w = o[7]*inv;
        float* dst = &emb[((size_t)b * FFEAT + f) * HDIM + 8 * i];
        *(float4*)dst       = v0;
        *(float4*)(dst + 4) = v1;
    }
}

// ---------------------------------------------------------------------------
// Tail: tiled GEMM + MHA core + final head (proven split kernels, unchanged).
// ---------------------------------------------------------------------------
struct GemmP {
    const float* X;
    const float* W[3];
    const float* B[3];
    const float* R;
    float* Y[3];
    int K;
    int Nfull;
    int act;
};

__global__ __launch_bounds__(256) void gemm_kernel(GemmP A)
{
    __shared__ float xs[64][65];
    __shared__ float ws[64][68];

    const int tid = threadIdx.x;
    const int tx  = tid & 15;
    const int ty  = tid >> 4;
    const int m0  = blockIdx.x * 64;
    const int n0  = blockIdx.y * 64;
    const int z   = blockIdx.z;

    const float* W = A.W[z];
    const float* Bv = A.B[z];
    float* Y = A.Y[z];
    const int K = A.K, Nfull = A.Nfull;

    float acc[4][4];
    #pragma unroll
    for (int i = 0; i < 4; ++i)
        #pragma unroll
        for (int j = 0; j < 4; ++j) acc[i][j] = 0.f;

    for (int kc = 0; kc < K; kc += 64) {
        for (int s = tid; s < 1024; s += 256) {
            int row = s >> 4, c4 = s & 15;
            float4 xv = *(const float4*)&A.X[(size_t)(m0 + row) * K + kc + 4*c4];
            xs[row][4*c4+0] = xv.x; xs[row][4*c4+1] = xv.y;
            xs[row][4*c4+2] = xv.z; xs[row][4*c4+3] = xv.w;
            float4 wv = *(const float4*)&W[(size_t)(kc + row) * Nfull + n0 + 4*c4];
            *(float4*)&ws[row][4*c4] = wv;
        }
        __syncthreads();
        #pragma unroll 16
        for (int k = 0; k < 64; ++k) {
            float a0 = xs[4*ty+0][k], a1 = xs[4*ty+1][k];
            float a2 = xs[4*ty+2][k], a3 = xs[4*ty+3][k];
            float4 wv = *(const float4*)&ws[k][4*tx];
            #pragma unroll
            for (int j = 0; j < 4; ++j) {
                float wj = (&wv.x)[j];
                acc[0][j] = fmaf(a0, wj, acc[0][j]);
                acc[1][j] = fmaf(a1, wj, acc[1][j]);
                acc[2][j] = fmaf(a2, wj, acc[2][j]);
                acc[3][j] = fmaf(a3, wj, acc[3][j]);
            }
        }
        __syncthreads();
    }

    float4 bias = *(const float4*)&Bv[n0 + 4*tx];
    #pragma unroll
    for (int i = 0; i < 4; ++i) {
        int row = m0 + 4*ty + i;
        float4 v;
        v.x = acc[i][0] + bias.x; v.y = acc[i][1] + bias.y;
        v.z = acc[i][2] + bias.z; v.w = acc[i][3] + bias.w;
        if (A.act) {
            v.x = fmaxf(v.x, 0.f); v.y = fmaxf(v.y, 0.f);
            v.z = fmaxf(v.z, 0.f); v.w = fmaxf(v.w, 0.f);
        }
        if (A.R) {
            float4 r4 = *(const float4*)&A.R[(size_t)row * Nfull + n0 + 4*tx];
            v.x += r4.x; v.y += r4.y; v.z += r4.z; v.w += r4.w;
        }
        *(float4*)&Y[(size_t)row * Nfull + n0 + 4*tx] = v;
    }
}

__global__ __launch_bounds__(256) void mha_core_kernel(
    const float* __restrict__ q, const float* __restrict__ k,
    const float* __restrict__ v, float* __restrict__ ctx)
{
    const int b  = blockIdx.x;
    const int hh = blockIdx.y;
    const int tid = threadIdx.x;

    __shared__ float qs[FFEAT][17];
    __shared__ float ks[FFEAT][17];
    __shared__ float vs[FFEAT][17];
    __shared__ float ps[FFEAT][77];

    for (int idx = tid; idx < FFEAT * DKH; idx += 256) {
        int i = idx >> 4, c = idx & 15;
        size_t g = ((size_t)b * FFEAT + i) * HDIM + hh * DKH + c;
        qs[i][c] = q[g]; ks[i][c] = k[g]; vs[i][c] = v[g];
    }
    __syncthreads();

    for (int idx = tid; idx < FFEAT * FFEAT; idx += 256) {
        int i = idx / FFEAT, j = idx % FFEAT;
        float acc = 0.f;
        #pragma unroll
        for (int c = 0; c < DKH; ++c) acc = fmaf(qs[i][c], ks[j][c], acc);
        ps[i][j] = acc * 0.25f;
    }
    __syncthreads();

    if (tid < FFEAT) {
        float mm = ps[tid][0];
        #pragma unroll 4
        for (int j = 1; j < FFEAT; ++j) mm = fmaxf(mm, ps[tid][j]);
        float ss = 0.f;
        #pragma unroll 4
        for (int j = 0; j < FFEAT; ++j) {
            float pv = __builtin_amdgcn_exp2f((ps[tid][j] - mm) * LOG2E);
            ps[tid][j] = pv; ss += pv;
        }
        float inv = 1.0f / ss;
        #pragma unroll 4
        for (int j = 0; j < FFEAT; ++j) ps[tid][j] *= inv;
    }
    __syncthreads();

    for (int idx = tid; idx < FFEAT * DKH; idx += 256) {
        int i = idx >> 4, c = idx & 15;
        float acc = 0.f;
        #pragma unroll 4
        for (int j = 0; j < FFEAT; ++j) acc = fmaf(ps[i][j], vs[j][c], acc);
        ctx[((size_t)b * FFEAT + i) * HDIM + hh * DKH + c] = acc;
    }
}

__global__ __launch_bounds__(128) void final_kernel(
    const float* __restrict__ ctx3, const float* __restrict__ fk,
    const float* __restrict__ fv,
    const float* __restrict__ faq, const float* __restrict__ fabq,
    const float* __restrict__ o0w, const float* __restrict__ o0b,
    const float* __restrict__ o1w, const float* __restrict__ o1b,
    float* __restrict__ out)
{
    const int b = blockIdx.x;
    const int tid = threadIdx.x;

    __shared__ float last[HDIM];
    __shared__ float fqs[HDIM];
    __shared__ float sm[FFEAT];
    __shared__ float vv[HDIM];
    __shared__ float hh[HDIM];
    __shared__ float redm[2], redp[2];

    if (tid < HDIM) last[tid] = ctx3[((size_t)b * FFEAT + FFEAT - 1) * HDIM + tid];
    __syncthreads();
    if (tid < HDIM) {
        float acc = fabq[tid];
        #pragma unroll 8
        for (int j = 0; j < HDIM; ++j) acc = fmaf(last[j], faq[j * HDIM + tid], acc);
        fqs[tid] = acc;
    }
    __syncthreads();

    float e = -3.0e38f;
    if (tid < FFEAT) {
        const float4* kr = (const float4*)&fk[((size_t)b * FFEAT + tid) * HDIM];
        float acc = 0.f;
        #pragma unroll
        for (int c4 = 0; c4 < 16; ++c4) {
            float4 kv = kr[c4];
            acc = fmaf(kv.x, fqs[4*c4+0], acc);
            acc = fmaf(kv.y, fqs[4*c4+1], acc);
            acc = fmaf(kv.z, fqs[4*c4+2], acc);
            acc = fmaf(kv.w, fqs[4*c4+3], acc);
        }
        e = acc;
    }
    float m = e;
    #pragma unroll
    for (int off = 32; off > 0; off >>= 1) m = fmaxf(m, __shfl_xor(m, off, 64));
    if ((tid & 63) == 0) redm[tid >> 6] = m;
    __syncthreads();
    m = fmaxf(redm[0], redm[1]);
    float p = (tid < FFEAT) ? __builtin_amdgcn_exp2f((e - m) * LOG2E) : 0.f;
    float s = p;
    #pragma unroll
    for (int off = 32; off > 0; off >>= 1) s += __shfl_xor(s, off, 64);
    if ((tid & 63) == 0) redp[tid >> 6] = s;
    __syncthreads();
    s = redp[0] + redp[1];
    if (tid < FFEAT) sm[tid] = p / s;
    __syncthreads();

    if (tid < HDIM) {
        float acc = 0.f;
        for (int ff = 0; ff < FFEAT; ++ff)
            acc = fmaf(sm[ff], fv[((size_t)b * FFEAT + ff) * HDIM + tid], acc);
        vv[tid] = acc;
    }
    __syncthreads();
    if (tid < HDIM) {
        float acc = o0b[tid];
        #pragma unroll 8
        for (int j = 0; j < HDIM; ++j) acc = fmaf(vv[j], o0w[j * HDIM + tid], acc);
        hh[tid] = fmaxf(acc, 0.f);
    }
    __syncthreads();
    if (tid < 64) {
        float t = hh[tid] * o1w[tid];
        #pragma unroll
        for (int off = 32; off > 0; off >>= 1) t += __shfl_xor(t, off, 64);
        if (tid == 0) out[b] = fast_sigmoid(t + o1b[0]);
    }
}

__global__ void ws_report_kernel(float* out, int n, float ws_mib) {
    int i = blockIdx.x * blockDim.x + threadIdx.x;
    if (i < n) out[i] = ws_mib;
}

extern "C" void kernel_launch(void* const* d_in, const int* in_sizes, int n_in,
                              void* d_out, int out_size, void* d_ws, size_t ws_size,
                              hipStream_t stream)
{
    const float* x     = (const float*)d_in[0];
    const float* w_ih  = (const float*)d_in[1];
    const float* w_hh  = (const float*)d_in[2];
    const float* b_ih  = (const float*)d_in[3];
    const float* b_hh  = (const float*)d_in[4];
    const float* attWt = (const float*)d_in[5];
    const float* attWx = (const float*)d_in[6];
    const float* attRt = (const float*)d_in[7];
    const float* wq    = (const float*)d_in[8];
    const float* bq    = (const float*)d_in[9];
    const float* wk    = (const float*)d_in[10];
    const float* bk    = (const float*)d_in[11];
    const float* wv    = (const float*)d_in[12];
    const float* bv    = (const float*)d_in[13];
    const float* wo    = (const float*)d_in[14];
    const float* bo    = (const float*)d_in[15];
    const float* w1    = (const float*)d_in[16];
    const float* b1    = (const float*)d_in[17];
    const float* w2    = (const float*)d_in[18];
    const float* b2    = (const float*)d_in[19];
    const float* faq   = (const float*)d_in[20];
    const float* fabq  = (const float*)d_in[21];
    const float* fak   = (const float*)d_in[22];
    const float* fabk  = (const float*)d_in[23];
    const float* fav   = (const float*)d_in[24];
    const float* fabv  = (const float*)d_in[25];
    const float* o0w   = (const float*)d_in[26];
    const float* o0b   = (const float*)d_in[27];
    const float* o1w   = (const float*)d_in[28];
    const float* o1b   = (const float*)d_in[29];
    float* out = (float*)d_out;

    const size_t embwtil_bytes = (size_t)NROWS * HDIM * 4;   // 4.98 MB (aliased)
    const size_t R64           = (size_t)NROWS * HDIM;
    const size_t tail_bytes    = 12 * R64 * 4;               // 59.8 MB

    const int chunk_opts[6] = {76, 38, 19, 4, 2, 1};
    int FC = 0;
    for (int i = 0; i < 6; ++i) {
        size_t hs_b = (size_t)chunk_opts[i] * BBATCH * TT * HDIM * 2;
        size_t scratch = hs_b > tail_bytes ? hs_b : tail_bytes;
        if (embwtil_bytes + scratch <= ws_size) { FC = chunk_opts[i]; break; }
    }
    if (FC == 0) {
        ws_report_kernel<<<dim3((out_size + 255) / 256), dim3(256), 0, stream>>>(
            out, out_size, (float)((double)ws_size / (1024.0 * 1024.0)));
        return;
    }

    float* embwtil = (float*)d_ws;              // wtil during scan, emb after attn2
    char*  scratch = (char*)d_ws + embwtil_bytes;
    __hip_bfloat16* hs = (__hip_bfloat16*)scratch;

    for (int f0 = 0; f0 < FFEAT; f0 += FC) {
        int fc = (FFEAT - f0 < FC) ? (FFEAT - f0) : FC;
        gru_scan_kernel<<<dim3(16, fc), dim3(64), 0, stream>>>(
            x, w_ih, w_hh, b_ih, b_hh, attWt, attWx, f0, hs, embwtil);
        attn2_kernel<<<dim3(BBATCH / 4, fc), dim3(256), 0, stream>>>(
            hs, embwtil, attRt, f0, embwtil);
    }

    float* emb  = embwtil;
    float* ts   = (float*)scratch;
    float* q    = ts;
    float* k    = ts + 1*R64;
    float* v    = ts + 2*R64;
    float* ctx  = ts + 3*R64;
    float* ctx2 = ts + 4*R64;
    float* hid  = ts + 5*R64;
    float* ctx3 = ts + 9*R64;
    float* fk   = ts + 10*R64;
    float* fv   = ts + 11*R64;

    const int MB = NROWS / 64;

    {
        GemmP A = { emb, {wq, wk, wv}, {bq, bk, bv}, nullptr, {q, k, v}, 64, 64, 0 };
        gemm_kernel<<<dim3(MB, 1, 3), dim3(256), 0, stream>>>(A);
    }
    mha_core_kernel<<<dim3(BBATCH, NHEAD), dim3(256), 0, stream>>>(q, k, v, ctx);
    {
        GemmP A = { ctx, {wo, nullptr, nullptr}, {bo, nullptr, nullptr}, emb,
                    {ctx2, nullptr, nullptr}, 64, 64, 0 };
        gemm_kernel<<<dim3(MB, 1, 1), dim3(256), 0, stream>>>(A);
    }
    {
        GemmP A = { ctx2, {w1, nullptr, nullptr}, {b1, nullptr, nullptr}, nullptr,
                    {hid, nullptr, nullptr}, 64, 256, 1 };
        gemm_kernel<<<dim3(MB, 4, 1), dim3(256), 0, stream>>>(A);
    }
    {
        GemmP A = { hid, {w2, nullptr, nullptr}, {b2, nullptr, nullptr}, ctx2,
                    {ctx3, nullptr, nullptr}, 256, 64, 0 };
        gemm_kernel<<<dim3(MB, 1, 1), dim3(256), 0, stream>>>(A);
    }
    {
        GemmP A = { ctx3, {fak, fav, nullptr}, {fabk, fabv, nullptr}, nullptr,
                    {fk, fv, nullptr}, 64, 64, 0 };
        gemm_kernel<<<dim3(MB, 1, 2), dim3(256), 0, stream>>>(A);
    }
    final_kernel<<<dim3(BBATCH), dim3(128), 0, stream>>>(
        ctx3, fk, fv, faq, fabq, o0w, o0b, o1w, o1b, out);
}

// Round 12
// 563.756 us; speedup vs baseline: 1.4531x; 1.0017x over previous
//
#include <hip/hip_runtime.h>
#include <hip/hip_bf16.h>
#include <cstdint>
#include <cstddef>

#define TT 128
#define BBATCH 256
#define FFEAT 76
#define HDIM 64
#define NHEAD 4
#define DKH 16
#define DFF1 256
#define AH1 8
#define NROWS (BBATCH * FFEAT)   // 19456
#define FCP 38                   // pipelined chunk (2 chunks)

#define LOG2E 1.4426950408889634f

typedef __attribute__((ext_vector_type(8))) short bf16x8;
typedef __attribute__((ext_vector_type(4))) float f32x4;

__device__ __forceinline__ float fast_sigmoid(float v) {
    float p = __builtin_amdgcn_exp2f(-v * LOG2E);
    return __builtin_amdgcn_rcpf(1.0f + p);
}
__device__ __forceinline__ float fast_tanh(float v) {
    float p = __builtin_amdgcn_exp2f(v * (2.0f * LOG2E));
    return 1.0f - 2.0f * __builtin_amdgcn_rcpf(1.0f + p);
}
__device__ __forceinline__ short f2bf(float x) {
    __hip_bfloat16 h = __float2bfloat16(x);
    return *reinterpret_cast<short*>(&h);
}
__device__ __forceinline__ float bf2f(unsigned short s) {
    return __uint_as_float(((unsigned)s) << 16);
}
__device__ __forceinline__ unsigned pack_bf16(float a, float b) {
    unsigned ua = (unsigned)(unsigned short)f2bf(a);
    unsigned ub = (unsigned)(unsigned short)f2bf(b);
    return ua | (ub << 16);
}

// ---------------------------------------------------------------------------
// Shared per-wave attention body (pipelined): prefetch all 16 rows, recompute
// q = Wt^T h127 (from U[15], same bf16 values the gru epilogue used) and the
// lane's wtilde slice, run the R11 online-softmax, then write the 256-B emb
// row EMBEDDED at the start of the wave's OWN hs row (all reads precede the
// write per-wave -> race-free).
// ---------------------------------------------------------------------------
__device__ __forceinline__ void attn_wave(
    __hip_bfloat16* hs_chunk, const float* Wt, const float* Wx,
    const float* rate, int f, int f_loc, int b, int lane)
{
    const int g = lane >> 3;
    const int i = lane & 7;
    short* rowbase = (short*)hs_chunk + ((size_t)f_loc * BBATCH + b) * TT * HDIM;
    const uint4* basev = (const uint4*)rowbase;

    uint4 U[16];
    #pragma unroll
    for (int it = 0; it < 16; ++it)
        U[it] = basev[(it * 8 + g) * 8 + i];

    // q[a] = sum_u Wt[f][u][a] * h127[u]; lanes g==7 hold t=127 (units 8i..8i+7)
    float qv[8];
    {
        uint4 Uv = U[15];
        float h15[8];
        h15[0]=__uint_as_float(Uv.x<<16); h15[1]=__uint_as_float(Uv.x&0xffff0000u);
        h15[2]=__uint_as_float(Uv.y<<16); h15[3]=__uint_as_float(Uv.y&0xffff0000u);
        h15[4]=__uint_as_float(Uv.z<<16); h15[5]=__uint_as_float(Uv.z&0xffff0000u);
        h15[6]=__uint_as_float(Uv.w<<16); h15[7]=__uint_as_float(Uv.w&0xffff0000u);
        const float* wtp = Wt + (size_t)f * 512 + (size_t)(8 * i) * 8;
        #pragma unroll
        for (int a = 0; a < 8; ++a) qv[a] = 0.f;
        #pragma unroll
        for (int j = 0; j < 8; ++j)
            #pragma unroll
            for (int a = 0; a < 8; ++a)
                qv[a] = fmaf(h15[j], wtp[j * 8 + a], qv[a]);
        #pragma unroll
        for (int a = 0; a < 8; ++a) {          // reduce over i within g=7 octet
            qv[a] += __shfl_xor(qv[a], 1, 64);
            qv[a] += __shfl_xor(qv[a], 2, 64);
            qv[a] += __shfl_xor(qv[a], 4, 64);
            qv[a]  = __shfl(qv[a], 63, 64);    // broadcast full q to all lanes
        }
    }
    // wtilde slice: wv[j] = sum_a Wx[f][8i+j][a] * q[a]  (same inner order as R11)
    float wv[8];
    {
        const float* wxp = Wx + (size_t)f * 512 + (size_t)(8 * i) * 8;
        #pragma unroll
        for (int j = 0; j < 8; ++j) {
            float s2 = 0.f;
            #pragma unroll
            for (int a = 0; a < 8; ++a) s2 = fmaf(wxp[j * 8 + a], qv[a], s2);
            wv[j] = s2;
        }
    }
    const float rs = fast_sigmoid(rate[f]);

    float m = -1.0e30f, s = 0.f;
    float o[8];
    #pragma unroll
    for (int j = 0; j < 8; ++j) o[j] = 0.f;

    #pragma unroll
    for (int it = 0; it < 16; ++it) {
        const int t = it * 8 + g;
        uint4 Uv = U[it];
        float h[8];
        h[0] = __uint_as_float(Uv.x << 16); h[1] = __uint_as_float(Uv.x & 0xffff0000u);
        h[2] = __uint_as_float(Uv.y << 16); h[3] = __uint_as_float(Uv.y & 0xffff0000u);
        h[4] = __uint_as_float(Uv.z << 16); h[5] = __uint_as_float(Uv.z & 0xffff0000u);
        h[6] = __uint_as_float(Uv.w << 16); h[7] = __uint_as_float(Uv.w & 0xffff0000u);
        float dp = 0.f;
        #pragma unroll
        for (int j = 0; j < 8; ++j) dp = fmaf(h[j], wv[j], dp);
        dp += __shfl_xor(dp, 1, 64);
        dp += __shfl_xor(dp, 2, 64);
        dp += __shfl_xor(dp, 4, 64);
        float sig = fast_sigmoid(dp);
        float den = rs * (__logf(2.72f + (1.0f - sig)) * (float)(TT - t));
        float e = fmaxf(sig / den, 0.0f);
        float nm = fmaxf(m, e);
        float sc = __builtin_amdgcn_exp2f((m - nm) * LOG2E);
        float p  = __builtin_amdgcn_exp2f((e - nm) * LOG2E);
        s = fmaf(s, sc, p);
        #pragma unroll
        for (int j = 0; j < 8; ++j) o[j] = fmaf(o[j], sc, p * h[j]);
        m = nm;
    }
    #pragma unroll
    for (int k = 8; k <= 32; k <<= 1) {
        float om = __shfl_xor(m, k, 64);
        float os = __shfl_xor(s, k, 64);
        float nm = fmaxf(m, om);
        float sa = __builtin_amdgcn_exp2f((m - nm) * LOG2E);
        float sb = __builtin_amdgcn_exp2f((om - nm) * LOG2E);
        s = s * sa + os * sb;
        #pragma unroll
        for (int j = 0; j < 8; ++j) {
            float oo = __shfl_xor(o[j], k, 64);
            o[j] = o[j] * sa + oo * sb;
        }
        m = nm;
    }
    if (g == 0) {
        float inv = __builtin_amdgcn_rcpf(s);
        float4 v0, v1;
        v0.x = o[0]*inv; v0.y = o[1]*inv; v0.z = o[2]*inv; v0.w = o[3]*inv;
        v1.x = o[4]*inv; v1.y = o[5]*inv; v1.z = o[6]*inv; v1.w = o[7]*inv;
        float* edst = (float*)rowbase;     // embedded emb: first 256 B of own row
        *(float4*)&edst[8 * i]     = v0;
        *(float4*)&edst[8 * i + 4] = v1;
    }
}

// ---------------------------------------------------------------------------
// PIPELINED fused kernel: gru role (R11 scan minus wtil epilogue) for
// chunk k + attn role (attn_wave, 1 wave) for chunk k-1. R8-proven: attn
// blocks are free inside a gru dispatch window.
// ---------------------------------------------------------------------------
__global__ __launch_bounds__(64) void fused_gru_attn_kernel(
    const float* __restrict__ x, const float* __restrict__ w_ih,
    const float* __restrict__ w_hh, const float* __restrict__ b_ih,
    const float* __restrict__ b_hh, const float* __restrict__ Wt,
    const float* __restrict__ Wx, const float* __restrict__ rate,
    int ngru, int f0_gru, __hip_bfloat16* __restrict__ hs_w,
    int f0_att, __hip_bfloat16* hs_r)
{
    __shared__ float x_lds[TT][16];
    const int gid  = blockIdx.x;
    const int lane = threadIdx.x;

    if (gid < ngru) {
        // ---------------- GRU scan role (R11 scan, no epilogue) ----------------
        const int f_loc = gid >> 4;
        const int f     = f0_gru + f_loc;
        const int b0    = (gid & 15) * 16;
        const int c     = lane & 15;
        const int q     = lane >> 4;

        for (int i = lane; i < TT * 16; i += 64) {
            int t = i >> 4, b = i & 15;
            x_lds[t][b] = x[((size_t)t * BBATCH + b0 + b) * FFEAT + f];
        }
        __syncthreads();

        bf16x8 afr[12][2];
        {
            const float* whh_f = w_hh + (size_t)f * 192 * 64;
            #pragma unroll
            for (int nt = 0; nt < 12; ++nt) {
                int gate = nt >> 2, tt = nt & 3;
                int urow = (c >> 2) * 8 + (tt & 1) * 4 + (c & 3) + (tt >> 1) * 32;
                const float* row = whh_f + (size_t)(gate * 64 + urow) * 64;
                #pragma unroll
                for (int kq = 0; kq < 2; ++kq) {
                    bf16x8 fr;
                    #pragma unroll
                    for (int j = 0; j < 8; ++j) fr[j] = f2bf(row[kq * 32 + q * 8 + j]);
                    afr[nt][kq] = fr;
                }
            }
        }
        float wr[4][4], wz[4][4], wn[4][4], bnx[4][4];
        f32x4 biasv[12];
        #pragma unroll
        for (int tt = 0; tt < 4; ++tt) {
            #pragma unroll
            for (int r = 0; r < 4; ++r) {
                int u = q * 8 + (tt & 1) * 4 + r + (tt >> 1) * 32;
                wr[tt][r]  = w_ih[f*192 + u];
                wz[tt][r]  = w_ih[f*192 + 64 + u];
                wn[tt][r]  = w_ih[f*192 + 128 + u];
                bnx[tt][r] = b_ih[f*192 + 128 + u];
                biasv[tt][r]     = b_ih[f*192 + u]      + b_hh[f*192 + u];
                biasv[4 + tt][r] = b_ih[f*192 + 64 + u] + b_hh[f*192 + 64 + u];
                biasv[8 + tt][r] = b_hh[f*192 + 128 + u];
            }
        }

        float hprev[4][4];
        #pragma unroll
        for (int tt = 0; tt < 4; ++tt)
            #pragma unroll
            for (int r = 0; r < 4; ++r) hprev[tt][r] = 0.f;

        bf16x8 hb0 = {0,0,0,0,0,0,0,0};
        bf16x8 hb1 = {0,0,0,0,0,0,0,0};

        short* hs_b = (short*)hs_w + ((size_t)f_loc * BBATCH + b0 + c) * TT * HDIM;

        for (int t = 0; t < TT; ++t) {
            f32x4 acc[12];
            #pragma unroll
            for (int nt = 0; nt < 12; ++nt) {
                f32x4 a = __builtin_amdgcn_mfma_f32_16x16x32_bf16(afr[nt][0], hb0, biasv[nt], 0, 0, 0);
                acc[nt]  = __builtin_amdgcn_mfma_f32_16x16x32_bf16(afr[nt][1], hb1, a, 0, 0, 0);
            }

            float xv = x_lds[t][c];
            float hn4[4][4];
            #pragma unroll
            for (int tt = 0; tt < 4; ++tt) {
                #pragma unroll
                for (int r = 0; r < 4; ++r) {
                    float R  = fmaf(xv, wr[tt][r], acc[tt][r]);
                    float Z  = fmaf(xv, wz[tt][r], acc[4 + tt][r]);
                    float NX = fmaf(xv, wn[tt][r], bnx[tt][r]);
                    float rg = fast_sigmoid(R);
                    float zg = fast_sigmoid(Z);
                    float ng = fast_tanh(fmaf(rg, acc[8 + tt][r], NX));
                    float hn = fmaf(zg, hprev[tt][r] - ng, ng);
                    hprev[tt][r] = hn;
                    hn4[tt][r] = hn;
                }
            }
            {
                union { int4 i; bf16x8 v; } u0, u1;
                u0.i.x = pack_bf16(hn4[0][0], hn4[0][1]);
                u0.i.y = pack_bf16(hn4[0][2], hn4[0][3]);
                u0.i.z = pack_bf16(hn4[1][0], hn4[1][1]);
                u0.i.w = pack_bf16(hn4[1][2], hn4[1][3]);
                u1.i.x = pack_bf16(hn4[2][0], hn4[2][1]);
                u1.i.y = pack_bf16(hn4[2][2], hn4[2][3]);
                u1.i.z = pack_bf16(hn4[3][0], hn4[3][1]);
                u1.i.w = pack_bf16(hn4[3][2], hn4[3][3]);
                hb0 = u0.v; hb1 = u1.v;
            }
            short* dst = hs_b + (size_t)t * HDIM + q * 8;
            *(bf16x8*)dst = hb0;
            *(bf16x8*)(dst + 32) = hb1;
        }
    } else {
        // ---------------- attention role (1 wave per (b,f)) ----------------
        const int aid   = gid - ngru;
        const int b     = aid & 255;
        const int f_loc = aid >> 8;
        attn_wave(hs_r, Wt, Wx, rate, f0_att + f_loc, f_loc, b, lane);
    }
}

// standalone pipelined attention (drain launch, 4 waves/block)
__global__ __launch_bounds__(256) void attn2_p_kernel(
    __hip_bfloat16* hs_chunk, const float* __restrict__ Wt,
    const float* __restrict__ Wx, const float* __restrict__ rate, int f_base)
{
    const int w    = threadIdx.x >> 6;
    const int lane = threadIdx.x & 63;
    const int b    = blockIdx.x * 4 + w;
    const int f_loc = blockIdx.y;
    attn_wave(hs_chunk, Wt, Wx, rate, f_base + f_loc, f_loc, b, lane);
}

// bounce: rescue embedded emb of hs0 rows 0..303 (they lie inside the final
// emb dest region) into dead row-middles of rows 400..703.
__global__ __launch_bounds__(64) void bounce_kernel(float* hs0f)
{
    const int k = blockIdx.x;                 // 0..303
    hs0f[(size_t)(400 + k) * 4096 + 2048 + threadIdx.x] =
        hs0f[(size_t)k * 4096 + threadIdx.x];
}

// compact: gather embedded emb rows (both chunks) into standard emb layout
// at d_ws. All sources verified disjoint from the dest region.
__global__ __launch_bounds__(64) void compact_kernel(
    const float* hs0f, const float* hs1f, float* emb)
{
    const int j = blockIdx.x;                 // 0..19455
    const int f = j >> 8;
    const int b = j & 255;
    const int chunk = (f >= FCP);
    const int f_loc = chunk ? f - FCP : f;
    const size_t row = (size_t)f_loc * BBATCH + b;
    const float* base = chunk ? hs1f : hs0f;
    size_t off = (!chunk && row <= 303)
               ? ((size_t)(400 + row) * 4096 + 2048)
               : row * 4096;
    emb[((size_t)b * FFEAT + f) * HDIM + threadIdx.x] = base[off + threadIdx.x];
}

// ---------------------------------------------------------------------------
// FALLBACK kernels (verbatim R11)
// ---------------------------------------------------------------------------
__global__ __launch_bounds__(64) void gru_scan_kernel(
    const float* __restrict__ x, const float* __restrict__ w_ih,
    const float* __restrict__ w_hh, const float* __restrict__ b_ih,
    const float* __restrict__ b_hh, const float* __restrict__ Wt,
    const float* __restrict__ Wx, int f_base,
    __hip_bfloat16* __restrict__ hs, float* __restrict__ wtil)
{
    const int f_loc = blockIdx.y;
    const int f     = f_base + f_loc;
    const int b0    = blockIdx.x * 16;
    const int lane  = threadIdx.x;
    const int c     = lane & 15;
    const int q     = lane >> 4;

    __shared__ float x_lds[TT][16];
    __shared__ float wt_s[64][8];
    __shared__ float wx_s[64][8];
    __shared__ short hx[16][72];
    __shared__ float q_s[16][8];

    for (int i = lane; i < TT * 16; i += 64) {
        int t = i >> 4, b = i & 15;
        x_lds[t][b] = x[((size_t)t * BBATCH + b0 + b) * FFEAT + f];
    }
    for (int i = lane; i < 512; i += 64) {
        ((float*)wt_s)[i] = Wt[(size_t)f * 512 + i];
        ((float*)wx_s)[i] = Wx[(size_t)f * 512 + i];
    }
    __syncthreads();

    bf16x8 afr[12][2];
    {
        const float* whh_f = w_hh + (size_t)f * 192 * 64;
        #pragma unroll
        for (int nt = 0; nt < 12; ++nt) {
            int gate = nt >> 2, tt = nt & 3;
            int urow = (c >> 2) * 8 + (tt & 1) * 4 + (c & 3) + (tt >> 1) * 32;
            const float* row = whh_f + (size_t)(gate * 64 + urow) * 64;
            #pragma unroll
            for (int kq = 0; kq < 2; ++kq) {
                bf16x8 fr;
                #pragma unroll
                for (int j = 0; j < 8; ++j) fr[j] = f2bf(row[kq * 32 + q * 8 + j]);
                afr[nt][kq] = fr;
            }
        }
    }
    float wr[4][4], wz[4][4], wn[4][4], bnx[4][4];
    f32x4 biasv[12];
    #pragma unroll
    for (int tt = 0; tt < 4; ++tt) {
        #pragma unroll
        for (int r = 0; r < 4; ++r) {
            int u = q * 8 + (tt & 1) * 4 + r + (tt >> 1) * 32;
            wr[tt][r]  = w_ih[f*192 + u];
            wz[tt][r]  = w_ih[f*192 + 64 + u];
            wn[tt][r]  = w_ih[f*192 + 128 + u];
            bnx[tt][r] = b_ih[f*192 + 128 + u];
            biasv[tt][r]     = b_ih[f*192 + u]      + b_hh[f*192 + u];
            biasv[4 + tt][r] = b_ih[f*192 + 64 + u] + b_hh[f*192 + 64 + u];
            biasv[8 + tt][r] = b_hh[f*192 + 128 + u];
        }
    }

    float hprev[4][4];
    #pragma unroll
    for (int tt = 0; tt < 4; ++tt)
        #pragma unroll
        for (int r = 0; r < 4; ++r) hprev[tt][r] = 0.f;

    bf16x8 hb0 = {0,0,0,0,0,0,0,0};
    bf16x8 hb1 = {0,0,0,0,0,0,0,0};

    short* hs_b = (short*)hs + ((size_t)f_loc * BBATCH + b0 + c) * TT * HDIM;

    for (int t = 0; t < TT; ++t) {
        f32x4 acc[12];
        #pragma unroll
        for (int nt = 0; nt < 12; ++nt) {
            f32x4 a = __builtin_amdgcn_mfma_f32_16x16x32_bf16(afr[nt][0], hb0, biasv[nt], 0, 0, 0);
            acc[nt]  = __builtin_amdgcn_mfma_f32_16x16x32_bf16(afr[nt][1], hb1, a, 0, 0, 0);
        }

        float xv = x_lds[t][c];
        float hn4[4][4];
        #pragma unroll
        for (int tt = 0; tt < 4; ++tt) {
            #pragma unroll
            for (int r = 0; r < 4; ++r) {
                float R  = fmaf(xv, wr[tt][r], acc[tt][r]);
                float Z  = fmaf(xv, wz[tt][r], acc[4 + tt][r]);
                float NX = fmaf(xv, wn[tt][r], bnx[tt][r]);
                float rg = fast_sigmoid(R);
                float zg = fast_sigmoid(Z);
                float ng = fast_tanh(fmaf(rg, acc[8 + tt][r], NX));
                float hn = fmaf(zg, hprev[tt][r] - ng, ng);
                hprev[tt][r] = hn;
                hn4[tt][r] = hn;
            }
        }
        {
            union { int4 i; bf16x8 v; } u0, u1;
            u0.i.x = pack_bf16(hn4[0][0], hn4[0][1]);
            u0.i.y = pack_bf16(hn4[0][2], hn4[0][3]);
            u0.i.z = pack_bf16(hn4[1][0], hn4[1][1]);
            u0.i.w = pack_bf16(hn4[1][2], hn4[1][3]);
            u1.i.x = pack_bf16(hn4[2][0], hn4[2][1]);
            u1.i.y = pack_bf16(hn4[2][2], hn4[2][3]);
            u1.i.z = pack_bf16(hn4[3][0], hn4[3][1]);
            u1.i.w = pack_bf16(hn4[3][2], hn4[3][3]);
            hb0 = u0.v; hb1 = u1.v;
        }
        short* dst = hs_b + (size_t)t * HDIM + q * 8;
        *(bf16x8*)dst = hb0;
        *(bf16x8*)(dst + 32) = hb1;
    }

    *(bf16x8*)&hx[c][q * 8]      = hb0;
    *(bf16x8*)&hx[c][32 + q * 8] = hb1;

    #pragma unroll
    for (int rr = 0; rr < 2; ++rr) {
        int role = rr * 64 + lane;
        int b = role >> 3, a = role & 7;
        float s = 0.f;
        #pragma unroll 8
        for (int j = 0; j < 64; ++j)
            s = fmaf(bf2f((unsigned short)hx[b][j]), wt_s[j][a], s);
        q_s[b][a] = s;
    }
    {
        int b = lane >> 2, jb = (lane & 3) * 16;
        float qreg[8];
        #pragma unroll
        for (int a = 0; a < 8; ++a) qreg[a] = q_s[b][a];
        float* wt_out = wtil + ((size_t)(b0 + b) * FFEAT + f) * HDIM + jb;
        #pragma unroll
        for (int j4 = 0; j4 < 4; ++j4) {
            float4 v;
            #pragma unroll
            for (int jj = 0; jj < 4; ++jj) {
                int j = jb + j4 * 4 + jj;
                float s = 0.f;
                #pragma unroll
                for (int a = 0; a < 8; ++a) s = fmaf(wx_s[j][a], qreg[a], s);
                (&v.x)[jj] = s;
            }
            *(float4*)&wt_out[j4 * 4] = v;
        }
    }
}

__global__ __launch_bounds__(256) void attn2_kernel(
    const __hip_bfloat16* __restrict__ hs, const float* wtil,
    const float* __restrict__ rate, int f_base, float* emb)
{
    const int w     = threadIdx.x >> 6;
    const int lane  = threadIdx.x & 63;
    const int b     = blockIdx.x * 4 + w;
    const int f_loc = blockIdx.y;
    const int f     = f_base + f_loc;
    const int g     = lane >> 3;
    const int i     = lane & 7;

    const uint4* basev = (const uint4*)((const short*)hs +
                          ((size_t)f_loc * BBATCH + b) * TT * HDIM);

    uint4 U[16];
    #pragma unroll
    for (int it = 0; it < 16; ++it)
        U[it] = basev[(it * 8 + g) * 8 + i];

    float wv[8];
    {
        const float4* src = (const float4*)(wtil + ((size_t)b * FFEAT + f) * HDIM + 8 * i);
        float4 a = src[0], c2 = src[1];
        wv[0]=a.x; wv[1]=a.y; wv[2]=a.z; wv[3]=a.w;
        wv[4]=c2.x; wv[5]=c2.y; wv[6]=c2.z; wv[7]=c2.w;
    }
    const float rs = fast_sigmoid(rate[f]);

    float m = -1.0e30f, s = 0.f;
    float o[8];
    #pragma unroll
    for (int j = 0; j < 8; ++j) o[j] = 0.f;

    #pragma unroll
    for (int it = 0; it < 16; ++it) {
        const int t = it * 8 + g;
        uint4 Uv = U[it];
        float h[8];
        h[0] = __uint_as_float(Uv.x << 16); h[1] = __uint_as_float(Uv.x & 0xffff0000u);
        h[2] = __uint_as_float(Uv.y << 16); h[3] = __uint_as_float(Uv.y & 0xffff0000u);
        h[4] = __uint_as_float(Uv.z << 16); h[5] = __uint_as_float(Uv.z & 0xffff0000u);
        h[6] = __uint_as_float(Uv.w << 16); h[7] = __uint_as_float(Uv.w & 0xffff0000u);
        float dp = 0.f;
        #pragma unroll
        for (int j = 0; j < 8; ++j) dp = fmaf(h[j], wv[j], dp);
        dp += __shfl_xor(dp, 1, 64);
        dp += __shfl_xor(dp, 2, 64);
        dp += __shfl_xor(dp, 4, 64);
        float sig = fast_sigmoid(dp);
        float den = rs * (__logf(2.72f + (1.0f - sig)) * (float)(TT - t));
        float e = fmaxf(sig / den, 0.0f);
        float nm = fmaxf(m, e);
        float sc = __builtin_amdgcn_exp2f((m - nm) * LOG2E);
        float p  = __builtin_amdgcn_exp2f((e - nm) * LOG2E);
        s = fmaf(s, sc, p);
        #pragma unroll
        for (int j = 0; j < 8; ++j) o[j] = fmaf(o[j], sc, p * h[j]);
        m = nm;
    }
    #pragma unroll
    for (int k = 8; k <= 32; k <<= 1) {
        float om = __shfl_xor(m, k, 64);
        float os = __shfl_xor(s, k, 64);
        float nm = fmaxf(m, om);
        float sa = __builtin_amdgcn_exp2f((m - nm) * LOG2E);
        float sb = __builtin_amdgcn_exp2f((om - nm) * LOG2E);
        s = s * sa + os * sb;
        #pragma unroll
        for (int j = 0; j < 8; ++j) {
            float oo = __shfl_xor(o[j], k, 64);
            o[j] = o[j] * sa + oo * sb;
        }
        m = nm;
    }
    if (g == 0) {
        float inv = __builtin_amdgcn_rcpf(s);
        float4 v0, v1;
        v0.x = o[0]*inv; v0.y = o[1]*inv; v0.z = o[2]*inv; v0.w = o[3]*inv;
        v1.x = o[4]*inv; v1.y = o[5]*inv; v1.z = o[6]*inv; v1.w = o[7]*inv;
        float* dst = &emb[((size_t)b * FFEAT + f) * HDIM + 8 * i];
        *(float4*)dst       = v0;
        *(float4*)(dst + 4) = v1;
    }
}

// ---------------------------------------------------------------------------
// Tail: tiled GEMM + MHA core + final head (proven split kernels, unchanged).
// ---------------------------------------------------------------------------
struct GemmP {
    const float* X;
    const float* W[3];
    const float* B[3];
    const float* R;
    float* Y[3];
    int K;
    int Nfull;
    int act;
};

__global__ __launch_bounds__(256) void gemm_kernel(GemmP A)
{
    __shared__ float xs[64][65];
    __shared__ float ws[64][68];

    const int tid = threadIdx.x;
    const int tx  = tid & 15;
    const int ty  = tid >> 4;
    const int m0  = blockIdx.x * 64;
    const int n0  = blockIdx.y * 64;
    const int z   = blockIdx.z;

    const float* W = A.W[z];
    const float* Bv = A.B[z];
    float* Y = A.Y[z];
    const int K = A.K, Nfull = A.Nfull;

    float acc[4][4];
    #pragma unroll
    for (int i = 0; i < 4; ++i)
        #pragma unroll
        for (int j = 0; j < 4; ++j) acc[i][j] = 0.f;

    for (int kc = 0; kc < K; kc += 64) {
        for (int s = tid; s < 1024; s += 256) {
            int row = s >> 4, c4 = s & 15;
            float4 xv = *(const float4*)&A.X[(size_t)(m0 + row) * K + kc + 4*c4];
            xs[row][4*c4+0] = xv.x; xs[row][4*c4+1] = xv.y;
            xs[row][4*c4+2] = xv.z; xs[row][4*c4+3] = xv.w;
            float4 wv = *(const float4*)&W[(size_t)(kc + row) * Nfull + n0 + 4*c4];
            *(float4*)&ws[row][4*c4] = wv;
        }
        __syncthreads();
        #pragma unroll 16
        for (int k = 0; k < 64; ++k) {
            float a0 = xs[4*ty+0][k], a1 = xs[4*ty+1][k];
            float a2 = xs[4*ty+2][k], a3 = xs[4*ty+3][k];
            float4 wv = *(const float4*)&ws[k][4*tx];
            #pragma unroll
            for (int j = 0; j < 4; ++j) {
                float wj = (&wv.x)[j];
                acc[0][j] = fmaf(a0, wj, acc[0][j]);
                acc[1][j] = fmaf(a1, wj, acc[1][j]);
                acc[2][j] = fmaf(a2, wj, acc[2][j]);
                acc[3][j] = fmaf(a3, wj, acc[3][j]);
            }
        }
        __syncthreads();
    }

    float4 bias = *(const float4*)&Bv[n0 + 4*tx];
    #pragma unroll
    for (int i = 0; i < 4; ++i) {
        int row = m0 + 4*ty + i;
        float4 v;
        v.x = acc[i][0] + bias.x; v.y = acc[i][1] + bias.y;
        v.z = acc[i][2] + bias.z; v.w = acc[i][3] + bias.w;
        if (A.act) {
            v.x = fmaxf(v.x, 0.f); v.y = fmaxf(v.y, 0.f);
            v.z = fmaxf(v.z, 0.f); v.w = fmaxf(v.w, 0.f);
        }
        if (A.R) {
            float4 r4 = *(const float4*)&A.R[(size_t)row * Nfull + n0 + 4*tx];
            v.x += r4.x; v.y += r4.y; v.z += r4.z; v.w += r4.w;
        }
        *(float4*)&Y[(size_t)row * Nfull + n0 + 4*tx] = v;
    }
}

__global__ __launch_bounds__(256) void mha_core_kernel(
    const float* __restrict__ q, const float* __restrict__ k,
    const float* __restrict__ v, float* __restrict__ ctx)
{
    const int b  = blockIdx.x;
    const int hh = blockIdx.y;
    const int tid = threadIdx.x;

    __shared__ float qs[FFEAT][17];
    __shared__ float ks[FFEAT][17];
    __shared__ float vs[FFEAT][17];
    __shared__ float ps[FFEAT][77];

    for (int idx = tid; idx < FFEAT * DKH; idx += 256) {
        int i = idx >> 4, c = idx & 15;
        size_t g = ((size_t)b * FFEAT + i) * HDIM + hh * DKH + c;
        qs[i][c] = q[g]; ks[i][c] = k[g]; vs[i][c] = v[g];
    }
    __syncthreads();

    for (int idx = tid; idx < FFEAT * FFEAT; idx += 256) {
        int i = idx / FFEAT, j = idx % FFEAT;
        float acc = 0.f;
        #pragma unroll
        for (int c = 0; c < DKH; ++c) acc = fmaf(qs[i][c], ks[j][c], acc);
        ps[i][j] = acc * 0.25f;
    }
    __syncthreads();

    if (tid < FFEAT) {
        float mm = ps[tid][0];
        #pragma unroll 4
        for (int j = 1; j < FFEAT; ++j) mm = fmaxf(mm, ps[tid][j]);
        float ss = 0.f;
        #pragma unroll 4
        for (int j = 0; j < FFEAT; ++j) {
            float pv = __builtin_amdgcn_exp2f((ps[tid][j] - mm) * LOG2E);
            ps[tid][j] = pv; ss += pv;
        }
        float inv = 1.0f / ss;
        #pragma unroll 4
        for (int j = 0; j < FFEAT; ++j) ps[tid][j] *= inv;
    }
    __syncthreads();

    for (int idx = tid; idx < FFEAT * DKH; idx += 256) {
        int i = idx >> 4, c = idx & 15;
        float acc = 0.f;
        #pragma unroll 4
        for (int j = 0; j < FFEAT; ++j) acc = fmaf(ps[i][j], vs[j][c], acc);
        ctx[((size_t)b * FFEAT + i) * HDIM + hh * DKH + c] = acc;
    }
}

__global__ __launch_bounds__(128) void final_kernel(
    const float* __restrict__ ctx3, const float* __restrict__ fk,
    const float* __restrict__ fv,
    const float* __restrict__ faq, const float* __restrict__ fabq,
    const float* __restrict__ o0w, const float* __restrict__ o0b,
    const float* __restrict__ o1w, const float* __restrict__ o1b,
    float* __restrict__ out)
{
    const int b = blockIdx.x;
    const int tid = threadIdx.x;

    __shared__ float last[HDIM];
    __shared__ float fqs[HDIM];
    __shared__ float sm[FFEAT];
    __shared__ float vv[HDIM];
    __shared__ float hh[HDIM];
    __shared__ float redm[2], redp[2];

    if (tid < HDIM) last[tid] = ctx3[((size_t)b * FFEAT + FFEAT - 1) * HDIM + tid];
    __syncthreads();
    if (tid < HDIM) {
        float acc = fabq[tid];
        #pragma unroll 8
        for (int j = 0; j < HDIM; ++j) acc = fmaf(last[j], faq[j * HDIM + tid], acc);
        fqs[tid] = acc;
    }
    __syncthreads();

    float e = -3.0e38f;
    if (tid < FFEAT) {
        const float4* kr = (const float4*)&fk[((size_t)b * FFEAT + tid) * HDIM];
        float acc = 0.f;
        #pragma unroll
        for (int c4 = 0; c4 < 16; ++c4) {
            float4 kv = kr[c4];
            acc = fmaf(kv.x, fqs[4*c4+0], acc);
            acc = fmaf(kv.y, fqs[4*c4+1], acc);
            acc = fmaf(kv.z, fqs[4*c4+2], acc);
            acc = fmaf(kv.w, fqs[4*c4+3], acc);
        }
        e = acc;
    }
    float m = e;
    #pragma unroll
    for (int off = 32; off > 0; off >>= 1) m = fmaxf(m, __shfl_xor(m, off, 64));
    if ((tid & 63) == 0) redm[tid >> 6] = m;
    __syncthreads();
    m = fmaxf(redm[0], redm[1]);
    float p = (tid < FFEAT) ? __builtin_amdgcn_exp2f((e - m) * LOG2E) : 0.f;
    float s = p;
    #pragma unroll
    for (int off = 32; off > 0; off >>= 1) s += __shfl_xor(s, off, 64);
    if ((tid & 63) == 0) redp[tid >> 6] = s;
    __syncthreads();
    s = redp[0] + redp[1];
    if (tid < FFEAT) sm[tid] = p / s;
    __syncthreads();

    if (tid < HDIM) {
        float acc = 0.f;
        for (int ff = 0; ff < FFEAT; ++ff)
            acc = fmaf(sm[ff], fv[((size_t)b * FFEAT + ff) * HDIM + tid], acc);
        vv[tid] = acc;
    }
    __syncthreads();
    if (tid < HDIM) {
        float acc = o0b[tid];
        #pragma unroll 8
        for (int j = 0; j < HDIM; ++j) acc = fmaf(vv[j], o0w[j * HDIM + tid], acc);
        hh[tid] = fmaxf(acc, 0.f);
    }
    __syncthreads();
    if (tid < 64) {
        float t = hh[tid] * o1w[tid];
        #pragma unroll
        for (int off = 32; off > 0; off >>= 1) t += __shfl_xor(t, off, 64);
        if (tid == 0) out[b] = fast_sigmoid(t + o1b[0]);
    }
}

__global__ void ws_report_kernel(float* out, int n, float ws_mib) {
    int i = blockIdx.x * blockDim.x + threadIdx.x;
    if (i < n) out[i] = ws_mib;
}

static void run_tail(const float* emb, float* ts,
                     const float* wq, const float* bq, const float* wk2, const float* bk2,
                     const float* wv2, const float* bv2, const float* wo, const float* bo,
                     const float* w1, const float* b1, const float* w2, const float* b2,
                     const float* faq, const float* fabq, const float* fak, const float* fabk,
                     const float* fav, const float* fabv, const float* o0w, const float* o0b,
                     const float* o1w, const float* o1b, float* out, hipStream_t stream)
{
    const size_t R64 = (size_t)NROWS * HDIM;
    float* q    = ts;
    float* k    = ts + 1*R64;
    float* v    = ts + 2*R64;
    float* ctx  = ts + 3*R64;
    float* ctx2 = ts + 4*R64;
    float* hid  = ts + 5*R64;
    float* ctx3 = ts + 9*R64;
    float* fk   = ts + 10*R64;
    float* fv   = ts + 11*R64;
    const int MB = NROWS / 64;

    {
        GemmP A = { emb, {wq, wk2, wv2}, {bq, bk2, bv2}, nullptr, {q, k, v}, 64, 64, 0 };
        gemm_kernel<<<dim3(MB, 1, 3), dim3(256), 0, stream>>>(A);
    }
    mha_core_kernel<<<dim3(BBATCH, NHEAD), dim3(256), 0, stream>>>(q, k, v, ctx);
    {
        GemmP A = { ctx, {wo, nullptr, nullptr}, {bo, nullptr, nullptr}, emb,
                    {ctx2, nullptr, nullptr}, 64, 64, 0 };
        gemm_kernel<<<dim3(MB, 1, 1), dim3(256), 0, stream>>>(A);
    }
    {
        GemmP A = { ctx2, {w1, nullptr, nullptr}, {b1, nullptr, nullptr}, nullptr,
                    {hid, nullptr, nullptr}, 64, 256, 1 };
        gemm_kernel<<<dim3(MB, 4, 1), dim3(256), 0, stream>>>(A);
    }
    {
        GemmP A = { hid, {w2, nullptr, nullptr}, {b2, nullptr, nullptr}, ctx2,
                    {ctx3, nullptr, nullptr}, 256, 64, 0 };
        gemm_kernel<<<dim3(MB, 1, 1), dim3(256), 0, stream>>>(A);
    }
    {
        GemmP A = { ctx3, {fak, fav, nullptr}, {fabk, fabv, nullptr}, nullptr,
                    {fk, fv, nullptr}, 64, 64, 0 };
        gemm_kernel<<<dim3(MB, 1, 2), dim3(256), 0, stream>>>(A);
    }
    final_kernel<<<dim3(BBATCH), dim3(128), 0, stream>>>(
        ctx3, fk, fv, faq, fabq, o0w, o0b, o1w, o1b, out);
}

extern "C" void kernel_launch(void* const* d_in, const int* in_sizes, int n_in,
                              void* d_out, int out_size, void* d_ws, size_t ws_size,
                              hipStream_t stream)
{
    const float* x     = (const float*)d_in[0];
    const float* w_ih  = (const float*)d_in[1];
    const float* w_hh  = (const float*)d_in[2];
    const float* b_ih  = (const float*)d_in[3];
    const float* b_hh  = (const float*)d_in[4];
    const float* attWt = (const float*)d_in[5];
    const float* attWx = (const float*)d_in[6];
    const float* attRt = (const float*)d_in[7];
    const float* wq    = (const float*)d_in[8];
    const float* bq    = (const float*)d_in[9];
    const float* wk    = (const float*)d_in[10];
    const float* bk    = (const float*)d_in[11];
    const float* wv    = (const float*)d_in[12];
    const float* bv    = (const float*)d_in[13];
    const float* wo    = (const float*)d_in[14];
    const float* bo    = (const float*)d_in[15];
    const float* w1    = (const float*)d_in[16];
    const float* b1    = (const float*)d_in[17];
    const float* w2    = (const float*)d_in[18];
    const float* b2    = (const float*)d_in[19];
    const float* faq   = (const float*)d_in[20];
    const float* fabq  = (const float*)d_in[21];
    const float* fak   = (const float*)d_in[22];
    const float* fabk  = (const float*)d_in[23];
    const float* fav   = (const float*)d_in[24];
    const float* fabv  = (const float*)d_in[25];
    const float* o0w   = (const float*)d_in[26];
    const float* o0b   = (const float*)d_in[27];
    const float* o1w   = (const float*)d_in[28];
    const float* o1b   = (const float*)d_in[29];
    float* out = (float*)d_out;

    const size_t emb_bytes = (size_t)NROWS * HDIM * 4;                 // 4.98 MB
    const size_t hs_half   = (size_t)FCP * BBATCH * TT * HDIM * 2;     // 159.38 MB

    if (ws_size >= 2 * hs_half) {
        // ---------------- PIPELINED path (needs 318.77 MB) ----------------
        __hip_bfloat16* hs0 = (__hip_bfloat16*)d_ws;
        __hip_bfloat16* hs1 = (__hip_bfloat16*)((char*)d_ws + hs_half);

        // L1: gru(c0)
        fused_gru_attn_kernel<<<dim3(16 * FCP), dim3(64), 0, stream>>>(
            x, w_ih, w_hh, b_ih, b_hh, attWt, attWx, attRt,
            16 * FCP, 0, hs0, 0, hs1);
        // L2: gru(c1) + attn(c0, embedded) — attn hides in gru's latency window
        fused_gru_attn_kernel<<<dim3(16 * FCP + BBATCH * FCP), dim3(64), 0, stream>>>(
            x, w_ih, w_hh, b_ih, b_hh, attWt, attWx, attRt,
            16 * FCP, FCP, hs1, 0, hs0);
        // rescue embedded emb of hs0 rows 0..303 (overlap final emb region)
        bounce_kernel<<<dim3(304), dim3(64), 0, stream>>>((float*)hs0);
        // L3: attn(c1, embedded)
        attn2_p_kernel<<<dim3(BBATCH / 4, FCP), dim3(256), 0, stream>>>(
            hs1, attWt, attWx, attRt, FCP);
        // L4: gather embedded emb -> standard layout at d_ws
        float* emb = (float*)d_ws;
        compact_kernel<<<dim3(NROWS), dim3(64), 0, stream>>>(
            (const float*)hs0, (const float*)hs1, emb);

        float* ts = (float*)((char*)d_ws + emb_bytes);
        run_tail(emb, ts, wq, bq, wk, bk, wv, bv, wo, bo, w1, b1, w2, b2,
                 faq, fabq, fak, fabk, fav, fabv, o0w, o0b, o1w, o1b, out, stream);
        return;
    }

    // ---------------- FALLBACK path (verbatim R11) ----------------
    const size_t R64        = (size_t)NROWS * HDIM;
    const size_t tail_bytes = 12 * R64 * 4;

    const int chunk_opts[6] = {76, 38, 19, 4, 2, 1};
    int FC = 0;
    for (int i = 0; i < 6; ++i) {
        size_t hs_b = (size_t)chunk_opts[i] * BBATCH * TT * HDIM * 2;
        size_t scratch = hs_b > tail_bytes ? hs_b : tail_bytes;
        if (emb_bytes + scratch <= ws_size) { FC = chunk_opts[i]; break; }
    }
    if (FC == 0) {
        ws_report_kernel<<<dim3((out_size + 255) / 256), dim3(256), 0, stream>>>(
            out, out_size, (float)((double)ws_size / (1024.0 * 1024.0)));
        return;
    }

    float* embwtil = (float*)d_ws;
    char*  scratch = (char*)d_ws + emb_bytes;
    __hip_bfloat16* hs = (__hip_bfloat16*)scratch;

    for (int f0 = 0; f0 < FFEAT; f0 += FC) {
        int fc = (FFEAT - f0 < FC) ? (FFEAT - f0) : FC;
        gru_scan_kernel<<<dim3(16, fc), dim3(64), 0, stream>>>(
            x, w_ih, w_hh, b_ih, b_hh, attWt, attWx, f0, hs, embwtil);
        attn2_kernel<<<dim3(BBATCH / 4, fc), dim3(256), 0, stream>>>(
            hs, embwtil, attRt, f0, embwtil);
    }

    run_tail(embwtil, (float*)scratch, wq, bq, wk, bk, wv, bv, wo, bo, w1, b1, w2, b2,
             faq, fabq, fak, fabk, fav, fabv, o0w, o0b, o1w, o1b, out, stream);
}